// Round 8
// baseline (272.187 us; speedup 1.0000x reference)
//
#include <hip/hip_runtime.h>
#include <cstdint>

typedef __attribute__((ext_vector_type(8))) __bf16 bf16x8;
typedef __attribute__((ext_vector_type(4))) float f32x4;
typedef __attribute__((ext_vector_type(8))) unsigned short u16x8;
typedef __attribute__((ext_vector_type(4))) unsigned short u16x4;

__device__ __forceinline__ unsigned short f2bf(float f) {
    union { float f; unsigned u; } v; v.f = f;
    unsigned u = v.u;
    return (unsigned short)((u + 0x7FFFu + ((u >> 16) & 1u)) >> 16);
}

__device__ __forceinline__ void gload_lds16(const void* g, void* l) {
    auto gp = reinterpret_cast<__attribute__((address_space(1))) unsigned*>(
        reinterpret_cast<uintptr_t>(g));
    auto lp = reinterpret_cast<__attribute__((address_space(3))) unsigned*>(
        reinterpret_cast<uintptr_t>(l));
    __builtin_amdgcn_global_load_lds(gp, lp, 16, 0, 0);
}

// ---------------- fp32 -> bf16 cast (latents only now) ----------------
__global__ __launch_bounds__(256) void cvt_kernel(const float* __restrict__ in,
                                                  unsigned short* __restrict__ out, int n4) {
    int idx = blockIdx.x * 256 + threadIdx.x;
    int stride = gridDim.x * 256;
    for (int i = idx; i < n4; i += stride) {
        float4 v = ((const float4*)in)[i];
        u16x4 o;
        o.x = f2bf(v.x); o.y = f2bf(v.y); o.z = f2bf(v.z); o.w = f2bf(v.w);
        ((u16x4*)out)[i] = o;
    }
}

// ---------------- fp32 [R][C] -> bf16 [C][R] ----------------
__global__ __launch_bounds__(256) void transpose_cvt(const float* __restrict__ in,
                                                     unsigned short* __restrict__ out,
                                                     int R, int C) {
    __shared__ float t[32][33];
    int c0 = blockIdx.x * 32, r0 = blockIdx.y * 32;
    int tx = threadIdx.x, ty = threadIdx.y;
    for (int i = ty; i < 32; i += 8)
        t[i][tx] = in[(size_t)(r0 + i) * C + c0 + tx];
    __syncthreads();
    for (int i = ty; i < 32; i += 8)
        out[(size_t)(c0 + i) * R + r0 + tx] = f2bf(t[tx][i]);
}

// ---------------- pipelined 128x128 bf16 GEMM (triple-buffer, counted vmcnt) ----
__global__ __launch_bounds__(256) void gemm128p(const unsigned short* __restrict__ A,
                                                const unsigned short* __restrict__ Bt,
                                                void* __restrict__ C,
                                                const float* __restrict__ bias,
                                                int M, int N, int K, float scale, int split,
                                                int c_f32) {
    __shared__ unsigned short lds[3][2][4096];  // 48 KiB
    int ntx = N >> 7;
    int nwg = gridDim.x, bid = blockIdx.x, swz = bid;
    if ((nwg & 7) == 0) { int cpx = nwg >> 3; swz = (bid & 7) * cpx + (bid >> 3); }
    int m0 = (swz / ntx) << 7, n0 = (swz % ntx) << 7;
    int tid = threadIdx.x, lane = tid & 63, w = tid >> 6;
    int wm = w >> 1, wn = w & 1;
    int lr = lane & 15, lg = lane >> 4;
    int gq = lg ^ ((lr >> 1) & 3);
    int nkt = K >> 5;

    int arow = tid >> 2;
    int sgl = (tid & 3) ^ ((arow >> 1) & 3);
    int ra0 = m0 + arow;      if (ra0 > M - 1) ra0 = M - 1;
    int ra1 = m0 + 64 + arow; if (ra1 > M - 1) ra1 = M - 1;
    const unsigned short* a0 = A + (size_t)ra0 * K + (sgl << 3);
    const unsigned short* a1 = A + (size_t)ra1 * K + (sgl << 3);
    const unsigned short* b0 = Bt + (size_t)(n0 + arow) * K + (sgl << 3);
    const unsigned short* b1 = Bt + (size_t)(n0 + 64 + arow) * K + (sgl << 3);

    f32x4 acc[4][4] = {};

#define ST_A128(bi, kt) do { \
        gload_lds16(a0 + ((kt) << 5), &lds[bi][0][w << 9]); \
        gload_lds16(a1 + ((kt) << 5), &lds[bi][0][2048 + (w << 9)]); } while (0)
#define ST_B128(bi, kt) do { \
        gload_lds16(b0 + ((kt) << 5), &lds[bi][1][w << 9]); \
        gload_lds16(b1 + ((kt) << 5), &lds[bi][1][2048 + (w << 9)]); } while (0)

    ST_A128(0, 0); ST_B128(0, 0);
    ST_A128(1, 1); ST_B128(1, 1);

    int buf = 0;
    for (int t = 0; t < nkt; ++t) {
        asm volatile("s_waitcnt vmcnt(4) lgkmcnt(0)" ::: "memory");
        __builtin_amdgcn_sched_barrier(0);
        __builtin_amdgcn_s_barrier();
        __builtin_amdgcn_sched_barrier(0);
        int st = t + 2; if (st >= nkt) st = nkt - 1;
        int sbuf = buf + 2; if (sbuf >= 3) sbuf -= 3;
        ST_A128(sbuf, st);
        ST_B128(sbuf, st);
        const unsigned short* pa = &lds[buf][0][((wm << 6) + lr) * 32 + (gq << 3)];
        const unsigned short* pb = &lds[buf][1][((wn << 6) + lr) * 32 + (gq << 3)];
        bf16x8 af[4], bfr[4];
#pragma unroll
        for (int nt = 0; nt < 4; nt++) bfr[nt] = *(const bf16x8*)(pb + nt * 512);
#pragma unroll
        for (int mt = 0; mt < 4; mt++) af[mt] = *(const bf16x8*)(pa + mt * 512);
        __builtin_amdgcn_s_setprio(1);
#pragma unroll
        for (int mt = 0; mt < 4; mt++)
#pragma unroll
            for (int nt = 0; nt < 4; nt++)
                acc[mt][nt] = __builtin_amdgcn_mfma_f32_16x16x32_bf16(af[mt], bfr[nt], acc[mt][nt], 0, 0, 0);
        __builtin_amdgcn_s_setprio(0);
        buf++; if (buf == 3) buf = 0;
    }
#undef ST_A128
#undef ST_B128

#pragma unroll
    for (int mt = 0; mt < 4; mt++) {
#pragma unroll
        for (int nt = 0; nt < 4; nt++) {
            int col = n0 + (wn << 6) + (nt << 4) + lr;
            float sc = (col < split) ? scale : 1.0f;
            float bv = bias ? bias[col] : 0.0f;
#pragma unroll
            for (int r = 0; r < 4; r++) {
                int row = m0 + (wm << 6) + (mt << 4) + (lg << 2) + r;
                if (row < M) {
                    float v = acc[mt][nt][r] * sc + bv;
                    if (c_f32) ((float*)C)[(size_t)row * N + col] = v;
                    else       ((unsigned short*)C)[(size_t)row * N + col] = f2bf(v);
                }
            }
        }
    }
}

// ---------------- large GEMM with fused f32->bf16 A-conversion ----------------
// C[M][N] = bf16(X[M][K] f32) @ Bt[N][K]^T. 256x256 tile, BK=32, dbuf=2 (64 KiB LDS).
// A: global f32 -> regs -> cvt_pk_bf16 -> swizzled ds_write (T14 issue-early/write-late).
// B: swizzled gload_lds. 8 waves (2m x 4n), per-wave 128x64, acc[8][4].
// Ledger/iter: [LD_A(t+1) x4][vmcnt(4)=drain ST_B(t)][lgkm(0)][bar][ST_B(t+1) x2]
//              [ds_read x12][MFMA x32][vmcnt(2)=drain LD_A][cvt+ds_write A(t+1)].
// Pre-barrier lgkmcnt(0) guarantees all waves' reads/writes of the about-to-be-
// overwritten buffer are complete before any post-barrier write (r5 race fix).
// Requires M%256==0, N%256==0, K%32==0, K>=64.
__global__ __launch_bounds__(512, 2) void gemm256f(const float* __restrict__ X,
                                                   const unsigned short* __restrict__ Bt,
                                                   unsigned short* __restrict__ C,
                                                   int M, int N, int K) {
    __shared__ unsigned short lds[2][16384];  // [buf][A:0..8191 | B:8192..16383], 64 KiB
    int nkt = K >> 5;
    int ntx = N >> 8;
    int nwg = gridDim.x, bid = blockIdx.x, swz = bid;
    if ((nwg & 7) == 0) { int cpx = nwg >> 3; swz = (bid & 7) * cpx + (bid >> 3); }
    int m0 = (swz / ntx) << 8, n0 = (swz % ntx) << 8;
    int tid = threadIdx.x, lane = tid & 63, w = tid >> 6;
    int wm = w >> 2, wn = w & 3;
    int lr = lane & 15, lg = lane >> 4;
    int gq = lg ^ ((lr >> 1) & 3);

    // B staging via gload_lds (r2-verified mapping): thread -> B row tid>>2 (+128),
    // phys granule tid&3, inverse-swizzled global granule sgl.
    int srow = tid >> 2;
    int sgl = (tid & 3) ^ ((srow >> 1) & 3);
    const unsigned short* b0 = Bt + (size_t)(n0 + srow) * K + (sgl << 3);
    const unsigned short* b1 = Bt + (size_t)(n0 + 128 + srow) * K + (sgl << 3);

    // A reg staging: 4 chunks; chunk p: row = (tid>>3)+64p, float4 fch = tid&7 (k = fch*4..+3)
    int arow = tid >> 3;
    int fch = tid & 7;
    const float* xBase = X + (size_t)(m0 + arow) * K + (fch << 2);
    size_t xRowStep = (size_t)64 * K;
    // LDS elem offset: row*32 + physGranule*8 + (fch&1)*4; physGranule=(fch>>1)^((row>>1)&3)
    // (row+64p)>>1 adds 32p -> &3 unchanged, so offset step is exactly p*2048.
    int aoff0 = arow * 32 + ((((fch >> 1) ^ ((arow >> 1) & 3))) << 3) + ((fch & 1) << 2);

    f32x4 acc[8][4] = {};
    float4 a_st[4];

#define LD_A(kt) do { _Pragma("unroll") for (int p = 0; p < 4; p++) \
        a_st[p] = *(const float4*)(xBase + (size_t)p * xRowStep + ((kt) << 5)); } while (0)
#define CVT_WRITE_A(bi) do { _Pragma("unroll") for (int p = 0; p < 4; p++) { \
        unsigned lo_, hi_; \
        asm volatile("v_cvt_pk_bf16_f32 %0, %1, %2" : "=v"(lo_) : "v"(a_st[p].x), "v"(a_st[p].y)); \
        asm volatile("v_cvt_pk_bf16_f32 %0, %1, %2" : "=v"(hi_) : "v"(a_st[p].z), "v"(a_st[p].w)); \
        uint2 u_; u_.x = lo_; u_.y = hi_; \
        *(uint2*)(&lds[bi][aoff0 + p * 2048]) = u_; } } while (0)
#define ST_B(bi, kt) do { \
        gload_lds16(b0 + ((kt) << 5), &lds[bi][8192 + (w << 9)]); \
        gload_lds16(b1 + ((kt) << 5), &lds[bi][8192 + 4096 + (w << 9)]); } while (0)

    // prologue: A(0) -> regs -> buf0; B(0) staged (the 2 newest vmem ops)
    LD_A(0);
    asm volatile("s_waitcnt vmcnt(0)" ::: "memory");
    CVT_WRITE_A(0);
    ST_B(0, 0);

    for (int t = 0; t < nkt; ++t) {
        int cur = t & 1, nxt = cur ^ 1;
        int tn = t + 1; if (tn >= nkt) tn = nkt - 1;

        LD_A(tn);                                   // A(t+1) -> regs (issue early)
        __builtin_amdgcn_sched_barrier(0);
        asm volatile("s_waitcnt vmcnt(4) lgkmcnt(0)" ::: "memory");  // drain ST_B(t); my reads(t-1)+writes A(t)
        __builtin_amdgcn_sched_barrier(0);
        __builtin_amdgcn_s_barrier();               // tile t published; buf(nxt) free
        __builtin_amdgcn_sched_barrier(0);

        ST_B(nxt, tn);                              // B(t+1) -> LDS

        const unsigned short* pa = &lds[cur][((wm << 7) + lr) * 32 + (gq << 3)];
        const unsigned short* pb = &lds[cur][8192 + ((wn << 6) + lr) * 32 + (gq << 3)];
        bf16x8 af[8], bfr[4];
#pragma unroll
        for (int nt = 0; nt < 4; nt++) bfr[nt] = *(const bf16x8*)(pb + nt * 512);
#pragma unroll
        for (int mt = 0; mt < 8; mt++) af[mt] = *(const bf16x8*)(pa + mt * 512);

        __builtin_amdgcn_s_setprio(1);
#pragma unroll
        for (int mt = 0; mt < 8; mt++)
#pragma unroll
            for (int nt = 0; nt < 4; nt++)
                acc[mt][nt] = __builtin_amdgcn_mfma_f32_16x16x32_bf16(af[mt], bfr[nt], acc[mt][nt], 0, 0, 0);
        __builtin_amdgcn_s_setprio(0);

        asm volatile("s_waitcnt vmcnt(2)" ::: "memory");  // drain LD_A(t+1) (leaves ST_B(t+1))
        __builtin_amdgcn_sched_barrier(0);
        CVT_WRITE_A(nxt);                           // write-late into buf(t+1)
    }
#undef LD_A
#undef CVT_WRITE_A
#undef ST_B

#pragma unroll
    for (int mt = 0; mt < 8; mt++) {
#pragma unroll
        for (int nt = 0; nt < 4; nt++) {
            int col = n0 + (wn << 6) + (nt << 4) + lr;
            size_t rbase = (size_t)(m0 + (wm << 7) + (mt << 4) + (lg << 2));
#pragma unroll
            for (int r = 0; r < 4; r++)
                C[(rbase + r) * N + col] = f2bf(acc[mt][nt][r]);
        }
    }
}

// ---------------- fused flash attention over 1088 keys (1024 media + 64 latent) ----------------
__global__ __launch_bounds__(256) void attn_kernel(const unsigned short* __restrict__ qg, int qstride,
                                                   const unsigned short* __restrict__ kvg,
                                                   const unsigned short* __restrict__ lkvg, int lstride,
                                                   unsigned short* __restrict__ og) {
    __shared__ unsigned short K_lds[64 * 72];
    __shared__ unsigned short V_lds[64 * 72];
    __shared__ unsigned short P_lds[4][16 * 72];
    int bm = blockIdx.x >> 4, h = blockIdx.x & 15;
    int tid = threadIdx.x, lane = tid & 63, w = tid >> 6;
    int lr = lane & 15, lg = lane >> 4;

    bf16x8 qf[2];
#pragma unroll
    for (int kk = 0; kk < 2; kk++)
        qf[kk] = *(const bf16x8*)(qg + (size_t)((w << 4) + lr) * qstride + (h << 6) + (kk << 5) + (lg << 3));

    f32x4 acc[4] = {};
    float m_run[4], l_run[4];
#pragma unroll
    for (int r = 0; r < 4; r++) { m_run[r] = -1e30f; l_run[r] = 0.0f; }

    int jrow = tid >> 2;
    int seg = (tid & 3) << 4;

    const unsigned short* s0 = kvg + (size_t)((bm << 10) + jrow) * 2048 + (h << 6);
    u16x8 k0 = *(const u16x8*)(s0 + seg);
    u16x8 k1 = *(const u16x8*)(s0 + seg + 8);
    u16x8 v0 = *(const u16x8*)(s0 + 1024 + seg);
    u16x8 v1 = *(const u16x8*)(s0 + 1024 + seg + 8);

    for (int t = 0; t < 17; t++) {
        *(u16x8*)(&K_lds[jrow * 72 + seg]) = k0;
        *(u16x8*)(&K_lds[jrow * 72 + seg + 8]) = k1;
#pragma unroll
        for (int c = 0; c < 8; c++) V_lds[(seg + c) * 72 + jrow] = v0[c];
#pragma unroll
        for (int c = 0; c < 8; c++) V_lds[(seg + 8 + c) * 72 + jrow] = v1[c];
        __syncthreads();

        u16x8 nk0 = k0, nk1 = k1, nv0 = v0, nv1 = v1;
        if (t < 16) {
            const unsigned short* src = (t < 15)
                ? kvg + (size_t)((bm << 10) + ((t + 1) << 6) + jrow) * 2048 + (h << 6)
                : lkvg + (size_t)jrow * lstride + (h << 6);
            nk0 = *(const u16x8*)(src + seg);
            nk1 = *(const u16x8*)(src + seg + 8);
            nv0 = *(const u16x8*)(src + 1024 + seg);
            nv1 = *(const u16x8*)(src + 1024 + seg + 8);
        }

        f32x4 s[4] = {};
#pragma unroll
        for (int jt = 0; jt < 4; jt++) {
#pragma unroll
            for (int kk = 0; kk < 2; kk++) {
                bf16x8 kf = *(const bf16x8*)(&K_lds[(size_t)((jt << 4) + lr) * 72 + (kk << 5) + (lg << 3)]);
                s[jt] = __builtin_amdgcn_mfma_f32_16x16x32_bf16(qf[kk], kf, s[jt], 0, 0, 0);
            }
        }
#pragma unroll
        for (int r = 0; r < 4; r++) {
            float mx = fmaxf(fmaxf(s[0][r], s[1][r]), fmaxf(s[2][r], s[3][r]));
            mx = fmaxf(mx, __shfl_xor(mx, 1));
            mx = fmaxf(mx, __shfl_xor(mx, 2));
            mx = fmaxf(mx, __shfl_xor(mx, 4));
            mx = fmaxf(mx, __shfl_xor(mx, 8));
            float nm = fmaxf(m_run[r], mx);
            float fct = __expf(m_run[r] - nm);
            m_run[r] = nm;
            float p0 = __expf(s[0][r] - nm);
            float p1 = __expf(s[1][r] - nm);
            float p2 = __expf(s[2][r] - nm);
            float p3 = __expf(s[3][r] - nm);
            float sum = p0 + p1 + p2 + p3;
            sum += __shfl_xor(sum, 1);
            sum += __shfl_xor(sum, 2);
            sum += __shfl_xor(sum, 4);
            sum += __shfl_xor(sum, 8);
            l_run[r] = l_run[r] * fct + sum;
#pragma unroll
            for (int dt = 0; dt < 4; dt++) acc[dt][r] *= fct;
            int prow = ((lg << 2) + r) * 72;
            P_lds[w][prow + lr]      = f2bf(p0);
            P_lds[w][prow + 16 + lr] = f2bf(p1);
            P_lds[w][prow + 32 + lr] = f2bf(p2);
            P_lds[w][prow + 48 + lr] = f2bf(p3);
        }
#pragma unroll
        for (int jkk = 0; jkk < 2; jkk++) {
            bf16x8 pf = *(const bf16x8*)(&P_lds[w][(size_t)lr * 72 + (jkk << 5) + (lg << 3)]);
#pragma unroll
            for (int dt = 0; dt < 4; dt++) {
                bf16x8 vf = *(const bf16x8*)(&V_lds[(size_t)((dt << 4) + lr) * 72 + (jkk << 5) + (lg << 3)]);
                acc[dt] = __builtin_amdgcn_mfma_f32_16x16x32_bf16(pf, vf, acc[dt], 0, 0, 0);
            }
        }
        __syncthreads();
        k0 = nk0; k1 = nk1; v0 = nv0; v1 = nv1;
    }
#pragma unroll
    for (int dt = 0; dt < 4; dt++) {
#pragma unroll
        for (int r = 0; r < 4; r++) {
            int i = (w << 4) + (lg << 2) + r;
            float v = acc[dt][r] / l_run[r];
            og[(size_t)((bm << 6) + i) * 1024 + (h << 6) + (dt << 4) + lr] = f2bf(v);
        }
    }
}

extern "C" void kernel_launch(void* const* d_in, const int* in_sizes, int n_in,
                              void* d_out, int out_size, void* d_ws, size_t ws_size,
                              hipStream_t stream) {
    const float* x       = (const float*)d_in[0];
    const float* latents = (const float*)d_in[1];
    const float* Wq      = (const float*)d_in[2];
    const float* Wkv     = (const float*)d_in[3];
    const float* Wout    = (const float*)d_in[4];
    const float* bout    = (const float*)d_in[5];
    char* ws = (char*)d_ws;
    unsigned short* kvb   = (unsigned short*)(ws + 67108864);      // 128 MiB [32768][2048]
    unsigned short* wqkvt = (unsigned short*)(ws + 201326592);     // 6 MiB   [3072][1024] (Wq^T | Wkv^T)
    unsigned short* wkvt  = wqkvt + 1024 * 1024;                   //         rows 1024..3071
    unsigned short* woutt = (unsigned short*)(ws + 207618048);     // 2 MiB   [1024][1024]
    unsigned short* latb  = (unsigned short*)(ws + 209715200);     // 128 KiB [64][1024]
    unsigned short* qlkvb = (unsigned short*)(ws + 209846272);     // 384 KiB [64][3072] (q | lk | lv)
    unsigned short* attnb = (unsigned short*)(ws + 210239488);     // 4 MiB   [2048][1024]

    cvt_kernel<<<64, 256, 0, stream>>>(latents, latb, 65536 / 4);
    dim3 tb(32, 8);
    transpose_cvt<<<dim3(32, 32), tb, 0, stream>>>(Wq, wqkvt, 1024, 1024);
    transpose_cvt<<<dim3(64, 32), tb, 0, stream>>>(Wkv, wkvt, 1024, 2048);
    transpose_cvt<<<dim3(32, 32), tb, 0, stream>>>(Wout, woutt, 1024, 1024);
    // [q | lkv] = latents @ [Wq | Wkv]; q-part (cols<1024) scaled by dh^-0.5
    gemm128p<<<24, 256, 0, stream>>>(latb, wqkvt, qlkvb, nullptr, 64, 3072, 1024, 0.125f, 1024, 0);
    // kv = bf16(x) @ Wkv  (dominant GEMM, fused f32->bf16 A-conversion)
    gemm256f<<<1024, 512, 0, stream>>>(x, wkvt, kvb, 32768, 2048, 1024);
    // fused attention
    attn_kernel<<<512, 256, 0, stream>>>(qlkvb, 3072, kvb, qlkvb + 1024, 3072, attnb);
    // out = attnout @ Wout + bout (fp32 out)
    gemm128p<<<128, 256, 0, stream>>>(attnb, woutt, (void*)d_out, bout, 2048, 1024, 1024, 1.0f, 0, 1);
}

// Round 9
// 257.676 us; speedup vs baseline: 1.0563x; 1.0563x over previous
//
#include <hip/hip_runtime.h>
#include <cstdint>

typedef __attribute__((ext_vector_type(8))) __bf16 bf16x8;
typedef __attribute__((ext_vector_type(4))) float f32x4;
typedef __attribute__((ext_vector_type(8))) unsigned short u16x8;
typedef __attribute__((ext_vector_type(4))) unsigned short u16x4;

__device__ __forceinline__ unsigned short f2bf(float f) {
    union { float f; unsigned u; } v; v.f = f;
    unsigned u = v.u;
    return (unsigned short)((u + 0x7FFFu + ((u >> 16) & 1u)) >> 16);
}

__device__ __forceinline__ void gload_lds16(const void* g, void* l) {
    auto gp = reinterpret_cast<__attribute__((address_space(1))) unsigned*>(
        reinterpret_cast<uintptr_t>(g));
    auto lp = reinterpret_cast<__attribute__((address_space(3))) unsigned*>(
        reinterpret_cast<uintptr_t>(l));
    __builtin_amdgcn_global_load_lds(gp, lp, 16, 0, 0);
}

// ---------------- fp32 -> bf16 cast ----------------
__global__ __launch_bounds__(256) void cvt_kernel(const float* __restrict__ in,
                                                  unsigned short* __restrict__ out, int n4) {
    int idx = blockIdx.x * 256 + threadIdx.x;
    int stride = gridDim.x * 256;
    for (int i = idx; i < n4; i += stride) {
        float4 v = ((const float4*)in)[i];
        u16x4 o;
        o.x = f2bf(v.x); o.y = f2bf(v.y); o.z = f2bf(v.z); o.w = f2bf(v.w);
        ((u16x4*)out)[i] = o;
    }
}

// ---------------- fp32 [R][C] -> bf16 [C][R] ----------------
__global__ __launch_bounds__(256) void transpose_cvt(const float* __restrict__ in,
                                                     unsigned short* __restrict__ out,
                                                     int R, int C) {
    __shared__ float t[32][33];
    int c0 = blockIdx.x * 32, r0 = blockIdx.y * 32;
    int tx = threadIdx.x, ty = threadIdx.y;
    for (int i = ty; i < 32; i += 8)
        t[i][tx] = in[(size_t)(r0 + i) * C + c0 + tx];
    __syncthreads();
    for (int i = ty; i < 32; i += 8)
        out[(size_t)(c0 + i) * R + r0 + tx] = f2bf(t[tx][i]);
}

// ---------------- pipelined 128x128 bf16 GEMM (triple-buffer, counted vmcnt) ----
// Epilogue: cols >= vstart (and vT != null) are written TRANSPOSED into vT[(col-vstart)*64 + row]
// (used to produce latent-V^T for the attention kernel).
__global__ __launch_bounds__(256) void gemm128p(const unsigned short* __restrict__ A,
                                                const unsigned short* __restrict__ Bt,
                                                void* __restrict__ C,
                                                const float* __restrict__ bias,
                                                unsigned short* __restrict__ vT,
                                                int M, int N, int K, float scale, int split,
                                                int c_f32, int vstart) {
    __shared__ unsigned short lds[3][2][4096];  // 48 KiB
    int ntx = N >> 7;
    int nwg = gridDim.x, bid = blockIdx.x, swz = bid;
    if ((nwg & 7) == 0) { int cpx = nwg >> 3; swz = (bid & 7) * cpx + (bid >> 3); }
    int m0 = (swz / ntx) << 7, n0 = (swz % ntx) << 7;
    int tid = threadIdx.x, lane = tid & 63, w = tid >> 6;
    int wm = w >> 1, wn = w & 1;
    int lr = lane & 15, lg = lane >> 4;
    int gq = lg ^ ((lr >> 1) & 3);
    int nkt = K >> 5;

    int arow = tid >> 2;
    int sgl = (tid & 3) ^ ((arow >> 1) & 3);
    int ra0 = m0 + arow;      if (ra0 > M - 1) ra0 = M - 1;
    int ra1 = m0 + 64 + arow; if (ra1 > M - 1) ra1 = M - 1;
    const unsigned short* a0 = A + (size_t)ra0 * K + (sgl << 3);
    const unsigned short* a1 = A + (size_t)ra1 * K + (sgl << 3);
    const unsigned short* b0 = Bt + (size_t)(n0 + arow) * K + (sgl << 3);
    const unsigned short* b1 = Bt + (size_t)(n0 + 64 + arow) * K + (sgl << 3);

    f32x4 acc[4][4] = {};

#define ST_A128(bi, kt) do { \
        gload_lds16(a0 + ((kt) << 5), &lds[bi][0][w << 9]); \
        gload_lds16(a1 + ((kt) << 5), &lds[bi][0][2048 + (w << 9)]); } while (0)
#define ST_B128(bi, kt) do { \
        gload_lds16(b0 + ((kt) << 5), &lds[bi][1][w << 9]); \
        gload_lds16(b1 + ((kt) << 5), &lds[bi][1][2048 + (w << 9)]); } while (0)

    ST_A128(0, 0); ST_B128(0, 0);
    ST_A128(1, 1); ST_B128(1, 1);

    int buf = 0;
    for (int t = 0; t < nkt; ++t) {
        asm volatile("s_waitcnt vmcnt(4) lgkmcnt(0)" ::: "memory");
        __builtin_amdgcn_sched_barrier(0);
        __builtin_amdgcn_s_barrier();
        __builtin_amdgcn_sched_barrier(0);
        int st = t + 2; if (st >= nkt) st = nkt - 1;
        int sbuf = buf + 2; if (sbuf >= 3) sbuf -= 3;
        ST_A128(sbuf, st);
        ST_B128(sbuf, st);
        const unsigned short* pa = &lds[buf][0][((wm << 6) + lr) * 32 + (gq << 3)];
        const unsigned short* pb = &lds[buf][1][((wn << 6) + lr) * 32 + (gq << 3)];
        bf16x8 af[4], bfr[4];
#pragma unroll
        for (int nt = 0; nt < 4; nt++) bfr[nt] = *(const bf16x8*)(pb + nt * 512);
#pragma unroll
        for (int mt = 0; mt < 4; mt++) af[mt] = *(const bf16x8*)(pa + mt * 512);
        __builtin_amdgcn_s_setprio(1);
#pragma unroll
        for (int mt = 0; mt < 4; mt++)
#pragma unroll
            for (int nt = 0; nt < 4; nt++)
                acc[mt][nt] = __builtin_amdgcn_mfma_f32_16x16x32_bf16(af[mt], bfr[nt], acc[mt][nt], 0, 0, 0);
        __builtin_amdgcn_s_setprio(0);
        buf++; if (buf == 3) buf = 0;
    }
#undef ST_A128
#undef ST_B128

#pragma unroll
    for (int mt = 0; mt < 4; mt++) {
#pragma unroll
        for (int nt = 0; nt < 4; nt++) {
            int col = n0 + (wn << 6) + (nt << 4) + lr;
            float sc = (col < split) ? scale : 1.0f;
            float bv = bias ? bias[col] : 0.0f;
#pragma unroll
            for (int r = 0; r < 4; r++) {
                int row = m0 + (wm << 6) + (mt << 4) + (lg << 2) + r;
                if (row < M) {
                    float v = acc[mt][nt][r] * sc + bv;
                    if (vT && col >= vstart) vT[(size_t)(col - vstart) * 64 + row] = f2bf(v);
                    else if (c_f32) ((float*)C)[(size_t)row * N + col] = v;
                    else ((unsigned short*)C)[(size_t)row * N + col] = f2bf(v);
                }
            }
        }
    }
}

// ---------------- large bf16 GEMM: 256x256, BK=64, 8-phase schedule (r7-verified) ------------
// Output split: cols 0..1023 (K-half) -> kb[32768][1024] row-major;
// cols 1024..2047 (V-half) -> vbT transposed: vbT[(bm*1024 + dg)*1024 + j], dg = col-1024,
// bm = row>>10, j = row&1023 (r=0..3 consecutive j -> packed u16x4 store).
// Blocks are column-uniform (BN=256 divides the 1024 split), so the branch is block-uniform.
__global__ __launch_bounds__(512, 2) void gemm256(const unsigned short* __restrict__ A,
                                                  const unsigned short* __restrict__ Bt,
                                                  unsigned short* __restrict__ kb,
                                                  unsigned short* __restrict__ vbT,
                                                  int M, int N, int K) {
    __shared__ unsigned short lds[2][32768];  // [buf][A:0..16383 | B:16384..32767], 128 KiB
    int nkt = K >> 6;
    int ntx = N >> 8;
    int nwg = gridDim.x, bid = blockIdx.x, swz = bid;
    if ((nwg & 7) == 0) { int cpx = nwg >> 3; swz = (bid & 7) * cpx + (bid >> 3); }
    int m0 = (swz / ntx) << 8, n0 = (swz % ntx) << 8;
    int tid = threadIdx.x, lane = tid & 63, w = tid >> 6;
    int wm = w >> 2, wn = w & 3;
    int lr = lane & 15, lg = lane >> 4;

    int srow = lane >> 3;
    int sg = (lane & 7) ^ srow;
    const unsigned short* aS = A + (size_t)(m0 + (w << 3) + srow) * K + (sg << 3);
    const unsigned short* bS = Bt + (size_t)(n0 + (w << 3) + srow) * K + (sg << 3);
    size_t rs64 = (size_t)64 * K;

    int baseA = (wm << 13) + lr * 64;
    int baseB = 16384 + (wn << 12) + lr * 64;
    int kg0 = (((0 << 2) + lg) ^ (lr & 7)) << 3;
    int kg1 = (((1 << 2) + lg) ^ (lr & 7)) << 3;

    f32x4 acc[8][4] = {};

#define ST_A(bi, kt) do { \
        gload_lds16(aS + ((size_t)(kt) << 6),          &lds[bi][(w << 9)]); \
        gload_lds16(aS + rs64 + ((size_t)(kt) << 6),   &lds[bi][4096 + (w << 9)]); \
        gload_lds16(aS + 2*rs64 + ((size_t)(kt) << 6), &lds[bi][8192 + (w << 9)]); \
        gload_lds16(aS + 3*rs64 + ((size_t)(kt) << 6), &lds[bi][12288 + (w << 9)]); } while (0)
#define ST_B(bi, kt) do { \
        gload_lds16(bS + ((size_t)(kt) << 6),          &lds[bi][16384 + (w << 9)]); \
        gload_lds16(bS + rs64 + ((size_t)(kt) << 6),   &lds[bi][20480 + (w << 9)]); \
        gload_lds16(bS + 2*rs64 + ((size_t)(kt) << 6), &lds[bi][24576 + (w << 9)]); \
        gload_lds16(bS + 3*rs64 + ((size_t)(kt) << 6), &lds[bi][28672 + (w << 9)]); } while (0)

    ST_A(0, 0);
    ST_B(0, 0);

    for (int t = 0; t < nkt; ++t) {
        int cur = t & 1, nxt = cur ^ 1;
        int st = t + 1; if (st >= nkt) st = nkt - 1;
        const unsigned short* L = &lds[cur][0];
        bf16x8 af[4], bfr[4];

        // ---- P0: stage A(t+1); vmcnt(4) publishes tile t; reads ks0 m0-3 + B ks0 ----
        ST_A(nxt, st);
        __builtin_amdgcn_sched_barrier(0);
        asm volatile("s_waitcnt vmcnt(4)" ::: "memory");
        __builtin_amdgcn_sched_barrier(0);
        __builtin_amdgcn_s_barrier();
        __builtin_amdgcn_sched_barrier(0);
#pragma unroll
        for (int nt = 0; nt < 4; nt++) bfr[nt] = *(const bf16x8*)(L + baseB + nt * 1024 + kg0);
#pragma unroll
        for (int i = 0; i < 4; i++) af[i] = *(const bf16x8*)(L + baseA + i * 1024 + kg0);
        asm volatile("s_waitcnt lgkmcnt(0)" ::: "memory");
        __builtin_amdgcn_sched_barrier(0);
        __builtin_amdgcn_s_setprio(1);
#pragma unroll
        for (int i = 0; i < 4; i++)
#pragma unroll
            for (int nt = 0; nt < 4; nt++)
                acc[i][nt] = __builtin_amdgcn_mfma_f32_16x16x32_bf16(af[i], bfr[nt], acc[i][nt], 0, 0, 0);
        __builtin_amdgcn_s_setprio(0);

        // ---- P1: stage B(t+1); reads ks0 m4-7 ----
        ST_B(nxt, st);
#pragma unroll
        for (int i = 0; i < 4; i++) af[i] = *(const bf16x8*)(L + baseA + (i + 4) * 1024 + kg0);
        asm volatile("s_waitcnt lgkmcnt(0)" ::: "memory");
        __builtin_amdgcn_sched_barrier(0);
        __builtin_amdgcn_s_setprio(1);
#pragma unroll
        for (int i = 0; i < 4; i++)
#pragma unroll
            for (int nt = 0; nt < 4; nt++)
                acc[i + 4][nt] = __builtin_amdgcn_mfma_f32_16x16x32_bf16(af[i], bfr[nt], acc[i + 4][nt], 0, 0, 0);
        __builtin_amdgcn_s_setprio(0);

        // ---- P2: reads ks1 m0-3 + B ks1 ----
#pragma unroll
        for (int nt = 0; nt < 4; nt++) bfr[nt] = *(const bf16x8*)(L + baseB + nt * 1024 + kg1);
#pragma unroll
        for (int i = 0; i < 4; i++) af[i] = *(const bf16x8*)(L + baseA + i * 1024 + kg1);
        asm volatile("s_waitcnt lgkmcnt(0)" ::: "memory");
        __builtin_amdgcn_sched_barrier(0);
        __builtin_amdgcn_s_setprio(1);
#pragma unroll
        for (int i = 0; i < 4; i++)
#pragma unroll
            for (int nt = 0; nt < 4; nt++)
                acc[i][nt] = __builtin_amdgcn_mfma_f32_16x16x32_bf16(af[i], bfr[nt], acc[i][nt], 0, 0, 0);
        __builtin_amdgcn_s_setprio(0);

        // ---- P3: reads ks1 m4-7; closing barrier after lgkmcnt ----
#pragma unroll
        for (int i = 0; i < 4; i++) af[i] = *(const bf16x8*)(L + baseA + (i + 4) * 1024 + kg1);
        asm volatile("s_waitcnt lgkmcnt(0)" ::: "memory");
        __builtin_amdgcn_sched_barrier(0);
        __builtin_amdgcn_s_barrier();
        __builtin_amdgcn_sched_barrier(0);
        __builtin_amdgcn_s_setprio(1);
#pragma unroll
        for (int i = 0; i < 4; i++)
#pragma unroll
            for (int nt = 0; nt < 4; nt++)
                acc[i + 4][nt] = __builtin_amdgcn_mfma_f32_16x16x32_bf16(af[i], bfr[nt], acc[i + 4][nt], 0, 0, 0);
        __builtin_amdgcn_s_setprio(0);
    }
#undef ST_A
#undef ST_B

    if (n0 < 1024) {
        // K half: row-major kb[32768][1024]
#pragma unroll
        for (int mt = 0; mt < 8; mt++) {
#pragma unroll
            for (int nt = 0; nt < 4; nt++) {
                int col = n0 + (wn << 6) + (nt << 4) + lr;
                size_t rbase = (size_t)(m0 + (wm << 7) + (mt << 4) + (lg << 2));
#pragma unroll
                for (int r = 0; r < 4; r++)
                    kb[(rbase + r) * 1024 + col] = f2bf(acc[mt][nt][r]);
            }
        }
    } else {
        // V half: transposed vbT[(bm*1024 + dg)*1024 + j]; r=0..3 are consecutive j
#pragma unroll
        for (int mt = 0; mt < 8; mt++) {
#pragma unroll
            for (int nt = 0; nt < 4; nt++) {
                int dg = n0 - 1024 + (wn << 6) + (nt << 4) + lr;
                int rbase = m0 + (wm << 7) + (mt << 4) + (lg << 2);
                int bm = rbase >> 10, j = rbase & 1023;
                u16x4 o;
                o.x = f2bf(acc[mt][nt][0]); o.y = f2bf(acc[mt][nt][1]);
                o.z = f2bf(acc[mt][nt][2]); o.w = f2bf(acc[mt][nt][3]);
                *(u16x4*)(&vbT[((size_t)(bm << 10) + dg) * 1024 + j]) = o;
            }
        }
    }
}

// ---------------- fused flash attention over 1088 keys (1024 media + 64 latent) ----------------
// K from kb[32768][1024]; V pre-transposed: vbT[(bm*1024 + h*64 + d)*1024 + j], latent lvT[d2][64 j].
// V staging is now 2 clean b128 writes (transpose cost moved to GEMM epilogues).
__global__ __launch_bounds__(256) void attn_kernel(const unsigned short* __restrict__ qg, int qstride,
                                                   const unsigned short* __restrict__ kb,
                                                   const unsigned short* __restrict__ vbT,
                                                   const unsigned short* __restrict__ lkg, int lstride,
                                                   const unsigned short* __restrict__ lvT,
                                                   unsigned short* __restrict__ og) {
    __shared__ unsigned short K_lds[64 * 72];
    __shared__ unsigned short V_lds[64 * 72];   // [d][j], stride 72
    __shared__ unsigned short P_lds[4][16 * 72];
    int bm = blockIdx.x >> 4, h = blockIdx.x & 15;
    int tid = threadIdx.x, lane = tid & 63, w = tid >> 6;
    int lr = lane & 15, lg = lane >> 4;

    bf16x8 qf[2];
#pragma unroll
    for (int kk = 0; kk < 2; kk++)
        qf[kk] = *(const bf16x8*)(qg + (size_t)((w << 4) + lr) * qstride + (h << 6) + (kk << 5) + (lg << 3));

    f32x4 acc[4] = {};
    float m_run[4], l_run[4];
#pragma unroll
    for (int r = 0; r < 4; r++) { m_run[r] = -1e30f; l_run[r] = 0.0f; }

    int jrow = tid >> 2;          // j for K, d for V^T
    int seg = (tid & 3) << 4;

    const unsigned short* k_s = kb + (size_t)((bm << 10) + jrow) * 1024 + (h << 6) + seg;
    const unsigned short* v_s = vbT + (size_t)((bm << 10) + (h << 6) + jrow) * 1024 + seg;
    u16x8 k0 = *(const u16x8*)(k_s);
    u16x8 k1 = *(const u16x8*)(k_s + 8);
    u16x8 v0 = *(const u16x8*)(v_s);
    u16x8 v1 = *(const u16x8*)(v_s + 8);

    for (int t = 0; t < 17; t++) {
        *(u16x8*)(&K_lds[jrow * 72 + seg]) = k0;
        *(u16x8*)(&K_lds[jrow * 72 + seg + 8]) = k1;
        *(u16x8*)(&V_lds[jrow * 72 + seg]) = v0;
        *(u16x8*)(&V_lds[jrow * 72 + seg + 8]) = v1;
        __syncthreads();

        u16x8 nk0 = k0, nk1 = k1, nv0 = v0, nv1 = v1;
        if (t < 16) {
            if (t < 15) {
                const unsigned short* ks = kb + (size_t)((bm << 10) + ((t + 1) << 6) + jrow) * 1024 + (h << 6) + seg;
                const unsigned short* vs = vbT + (size_t)((bm << 10) + (h << 6) + jrow) * 1024 + ((t + 1) << 6) + seg;
                nk0 = *(const u16x8*)(ks);
                nk1 = *(const u16x8*)(ks + 8);
                nv0 = *(const u16x8*)(vs);
                nv1 = *(const u16x8*)(vs + 8);
            } else {
                const unsigned short* ks = lkg + (size_t)jrow * lstride + (h << 6) + seg;
                const unsigned short* vs = lvT + (size_t)((h << 6) + jrow) * 64 + seg;
                nk0 = *(const u16x8*)(ks);
                nk1 = *(const u16x8*)(ks + 8);
                nv0 = *(const u16x8*)(vs);
                nv1 = *(const u16x8*)(vs + 8);
            }
        }

        f32x4 s[4] = {};
#pragma unroll
        for (int jt = 0; jt < 4; jt++) {
#pragma unroll
            for (int kk = 0; kk < 2; kk++) {
                bf16x8 kf = *(const bf16x8*)(&K_lds[(size_t)((jt << 4) + lr) * 72 + (kk << 5) + (lg << 3)]);
                s[jt] = __builtin_amdgcn_mfma_f32_16x16x32_bf16(qf[kk], kf, s[jt], 0, 0, 0);
            }
        }
#pragma unroll
        for (int r = 0; r < 4; r++) {
            float mx = fmaxf(fmaxf(s[0][r], s[1][r]), fmaxf(s[2][r], s[3][r]));
            mx = fmaxf(mx, __shfl_xor(mx, 1));
            mx = fmaxf(mx, __shfl_xor(mx, 2));
            mx = fmaxf(mx, __shfl_xor(mx, 4));
            mx = fmaxf(mx, __shfl_xor(mx, 8));
            float nm = fmaxf(m_run[r], mx);
            float fct = __expf(m_run[r] - nm);
            m_run[r] = nm;
            float p0 = __expf(s[0][r] - nm);
            float p1 = __expf(s[1][r] - nm);
            float p2 = __expf(s[2][r] - nm);
            float p3 = __expf(s[3][r] - nm);
            float sum = p0 + p1 + p2 + p3;
            sum += __shfl_xor(sum, 1);
            sum += __shfl_xor(sum, 2);
            sum += __shfl_xor(sum, 4);
            sum += __shfl_xor(sum, 8);
            l_run[r] = l_run[r] * fct + sum;
#pragma unroll
            for (int dt = 0; dt < 4; dt++) acc[dt][r] *= fct;
            int prow = ((lg << 2) + r) * 72;
            P_lds[w][prow + lr]      = f2bf(p0);
            P_lds[w][prow + 16 + lr] = f2bf(p1);
            P_lds[w][prow + 32 + lr] = f2bf(p2);
            P_lds[w][prow + 48 + lr] = f2bf(p3);
        }
#pragma unroll
        for (int jkk = 0; jkk < 2; jkk++) {
            bf16x8 pf = *(const bf16x8*)(&P_lds[w][(size_t)lr * 72 + (jkk << 5) + (lg << 3)]);
#pragma unroll
            for (int dt = 0; dt < 4; dt++) {
                bf16x8 vf = *(const bf16x8*)(&V_lds[(size_t)((dt << 4) + lr) * 72 + (jkk << 5) + (lg << 3)]);
                acc[dt] = __builtin_amdgcn_mfma_f32_16x16x32_bf16(pf, vf, acc[dt], 0, 0, 0);
            }
        }
        __syncthreads();
        k0 = nk0; k1 = nk1; v0 = nv0; v1 = nv1;
    }
#pragma unroll
    for (int dt = 0; dt < 4; dt++) {
#pragma unroll
        for (int r = 0; r < 4; r++) {
            int i = (w << 4) + (lg << 2) + r;
            float v = acc[dt][r] / l_run[r];
            og[(size_t)((bm << 6) + i) * 1024 + (h << 6) + (dt << 4) + lr] = f2bf(v);
        }
    }
}

extern "C" void kernel_launch(void* const* d_in, const int* in_sizes, int n_in,
                              void* d_out, int out_size, void* d_ws, size_t ws_size,
                              hipStream_t stream) {
    const float* x       = (const float*)d_in[0];
    const float* latents = (const float*)d_in[1];
    const float* Wq      = (const float*)d_in[2];
    const float* Wkv     = (const float*)d_in[3];
    const float* Wout    = (const float*)d_in[4];
    const float* bout    = (const float*)d_in[5];
    char* ws = (char*)d_ws;
    unsigned short* xb    = (unsigned short*)(ws);                 // 64 MiB  [32768][1024]
    unsigned short* kb    = (unsigned short*)(ws + 67108864);      // 64 MiB  [32768][1024]
    unsigned short* vbT   = (unsigned short*)(ws + 134217728);     // 64 MiB  [32][1024 dg][1024 j]
    unsigned short* wqkvt = (unsigned short*)(ws + 201326592);     // 6 MiB   [3072][1024]
    unsigned short* wkvt  = wqkvt + 1024 * 1024;                   //         rows 1024..3071
    unsigned short* woutt = (unsigned short*)(ws + 207618048);     // 2 MiB   [1024][1024]
    unsigned short* latb  = (unsigned short*)(ws + 209715200);     // 128 KiB [64][1024]
    unsigned short* qlkvb = (unsigned short*)(ws + 209846272);     // 384 KiB [64][3072] (q | lk | --)
    unsigned short* attnb = (unsigned short*)(ws + 210239488);     // 4 MiB   [2048][1024]
    unsigned short* lvT   = (unsigned short*)(ws + 214433792);     // 128 KiB [1024 d2][64 j]

    cvt_kernel<<<2048, 256, 0, stream>>>(x, xb, 33554432 / 4);
    cvt_kernel<<<64, 256, 0, stream>>>(latents, latb, 65536 / 4);
    dim3 tb(32, 8);
    transpose_cvt<<<dim3(32, 32), tb, 0, stream>>>(Wq, wqkvt, 1024, 1024);
    transpose_cvt<<<dim3(64, 32), tb, 0, stream>>>(Wkv, wkvt, 1024, 2048);
    transpose_cvt<<<dim3(32, 32), tb, 0, stream>>>(Wout, woutt, 1024, 1024);
    // [q | lk | lv] = latents @ [Wq | Wkv]; q scaled; lv (cols>=2048) written transposed to lvT
    gemm128p<<<24, 256, 0, stream>>>(latb, wqkvt, qlkvb, nullptr, lvT, 64, 3072, 1024, 0.125f, 1024, 0, 2048);
    // kv = x @ Wkv: K half row-major to kb, V half transposed to vbT
    gemm256<<<1024, 512, 0, stream>>>(xb, wkvt, kb, vbT, 32768, 2048, 1024);
    // fused attention
    attn_kernel<<<512, 256, 0, stream>>>(qlkvb, 3072, kb, vbT, qlkvb + 1024, 3072, lvT, attnb);
    // out = attnout @ Wout + bout (fp32 out)
    gemm128p<<<128, 256, 0, stream>>>(attnb, woutt, (void*)d_out, bout, nullptr, 2048, 1024, 1024, 1.0f, 0, 1, 1 << 30);
}

// Round 10
// 241.863 us; speedup vs baseline: 1.1254x; 1.0654x over previous
//
#include <hip/hip_runtime.h>
#include <cstdint>

typedef __attribute__((ext_vector_type(8))) __bf16 bf16x8;
typedef __attribute__((ext_vector_type(4))) float f32x4;
typedef __attribute__((ext_vector_type(8))) unsigned short u16x8;
typedef __attribute__((ext_vector_type(4))) unsigned short u16x4;

__device__ __forceinline__ unsigned short f2bf(float f) {
    union { float f; unsigned u; } v; v.f = f;
    unsigned u = v.u;
    return (unsigned short)((u + 0x7FFFu + ((u >> 16) & 1u)) >> 16);
}

__device__ __forceinline__ void gload_lds16(const void* g, void* l) {
    auto gp = reinterpret_cast<__attribute__((address_space(1))) unsigned*>(
        reinterpret_cast<uintptr_t>(g));
    auto lp = reinterpret_cast<__attribute__((address_space(3))) unsigned*>(
        reinterpret_cast<uintptr_t>(l));
    __builtin_amdgcn_global_load_lds(gp, lp, 16, 0, 0);
}

// ---------------- fused prep: cvt x | cvt latents | W transposes (one launch) ----------------
// blocks [0,2048): cvt x; [2048,2112): cvt latents; [2112,3136): Wq^T; [3136,5184): Wkv^T;
// [5184,6208): Wout^T. Each block entirely in one branch (block-uniform; barriers safe).
__global__ __launch_bounds__(256) void prep(const float* __restrict__ x,
                                            const float* __restrict__ latents,
                                            const float* __restrict__ Wq,
                                            const float* __restrict__ Wkv,
                                            const float* __restrict__ Wout,
                                            unsigned short* __restrict__ xb,
                                            unsigned short* __restrict__ latb,
                                            unsigned short* __restrict__ wqkvt,
                                            unsigned short* __restrict__ wkvt,
                                            unsigned short* __restrict__ woutt) {
    int b = blockIdx.x, tid = threadIdx.x;
    if (b < 2048) {                       // cvt x: 33554432 elems = 8388608 float4
        int idx = b * 256 + tid, stride = 2048 * 256;
        for (int i = idx; i < 8388608; i += stride) {
            float4 v = ((const float4*)x)[i];
            u16x4 o;
            o.x = f2bf(v.x); o.y = f2bf(v.y); o.z = f2bf(v.z); o.w = f2bf(v.w);
            ((u16x4*)xb)[i] = o;
        }
        return;
    }
    b -= 2048;
    if (b < 64) {                         // cvt latents: 16384 float4
        int i = b * 256 + tid;
        float4 v = ((const float4*)latents)[i];
        u16x4 o;
        o.x = f2bf(v.x); o.y = f2bf(v.y); o.z = f2bf(v.z); o.w = f2bf(v.w);
        ((u16x4*)latb)[i] = o;
        return;
    }
    b -= 64;
    const float* in; unsigned short* out; int R, C, bx, by;
    if (b < 1024)      { in = Wq;   out = wqkvt; R = 1024; C = 1024; bx = b & 31; by = b >> 5; }
    else if (b < 3072) { int v = b - 1024; in = Wkv;  out = wkvt;  R = 1024; C = 2048; bx = v & 63; by = v >> 6; }
    else               { int v = b - 3072; in = Wout; out = woutt; R = 1024; C = 1024; bx = v & 31; by = v >> 5; }
    __shared__ float t[32][33];
    int c0 = bx * 32, r0 = by * 32;
    int tx = tid & 31, ty = tid >> 5;
    for (int i = ty; i < 32; i += 8)
        t[i][tx] = in[(size_t)(r0 + i) * C + c0 + tx];
    __syncthreads();
    for (int i = ty; i < 32; i += 8)
        out[(size_t)(c0 + i) * R + r0 + tx] = f2bf(t[tx][i]);
}

// ---------------- pipelined 128x128 bf16 GEMM body (triple-buffer, counted vmcnt) ----
// tid is a VIRTUAL 256-thread id (callers with 512 threads pass tid&255: waves 4-7 mirror
// 0-3 — duplicate DMA/stores of identical data to identical addresses, barrier-safe).
// ldsbuf: 3*2*4096 u16 = 48 KiB provided by caller.
__device__ __forceinline__ void gemm128p_body(const unsigned short* __restrict__ A,
                                              const unsigned short* __restrict__ Bt,
                                              void* __restrict__ C,
                                              const float* __restrict__ bias,
                                              unsigned short* __restrict__ vT,
                                              int M, int N, int K, float scale, int split,
                                              int c_f32, int vstart,
                                              int tid, int bid, int nwg,
                                              unsigned short* ldsbuf) {
#define LDSP(bi, half) (ldsbuf + ((bi) * 2 + (half)) * 4096)
    int ntx = N >> 7;
    int swz = bid;
    if ((nwg & 7) == 0) { int cpx = nwg >> 3; swz = (bid & 7) * cpx + (bid >> 3); }
    int m0 = (swz / ntx) << 7, n0 = (swz % ntx) << 7;
    int lane = tid & 63, w = tid >> 6;
    int wm = w >> 1, wn = w & 1;
    int lr = lane & 15, lg = lane >> 4;
    int gq = lg ^ ((lr >> 1) & 3);
    int nkt = K >> 5;

    int arow = tid >> 2;
    int sgl = (tid & 3) ^ ((arow >> 1) & 3);
    int ra0 = m0 + arow;      if (ra0 > M - 1) ra0 = M - 1;
    int ra1 = m0 + 64 + arow; if (ra1 > M - 1) ra1 = M - 1;
    const unsigned short* a0 = A + (size_t)ra0 * K + (sgl << 3);
    const unsigned short* a1 = A + (size_t)ra1 * K + (sgl << 3);
    const unsigned short* b0 = Bt + (size_t)(n0 + arow) * K + (sgl << 3);
    const unsigned short* b1 = Bt + (size_t)(n0 + 64 + arow) * K + (sgl << 3);

    f32x4 acc[4][4] = {};

#define ST_A128(bi, kt) do { \
        gload_lds16(a0 + ((kt) << 5), LDSP(bi, 0) + (w << 9)); \
        gload_lds16(a1 + ((kt) << 5), LDSP(bi, 0) + 2048 + (w << 9)); } while (0)
#define ST_B128(bi, kt) do { \
        gload_lds16(b0 + ((kt) << 5), LDSP(bi, 1) + (w << 9)); \
        gload_lds16(b1 + ((kt) << 5), LDSP(bi, 1) + 2048 + (w << 9)); } while (0)

    ST_A128(0, 0); ST_B128(0, 0);
    ST_A128(1, 1); ST_B128(1, 1);

    int buf = 0;
    for (int t = 0; t < nkt; ++t) {
        asm volatile("s_waitcnt vmcnt(4) lgkmcnt(0)" ::: "memory");
        __builtin_amdgcn_sched_barrier(0);
        __builtin_amdgcn_s_barrier();
        __builtin_amdgcn_sched_barrier(0);
        int st = t + 2; if (st >= nkt) st = nkt - 1;
        int sbuf = buf + 2; if (sbuf >= 3) sbuf -= 3;
        ST_A128(sbuf, st);
        ST_B128(sbuf, st);
        const unsigned short* pa = LDSP(buf, 0) + ((wm << 6) + lr) * 32 + (gq << 3);
        const unsigned short* pb = LDSP(buf, 1) + ((wn << 6) + lr) * 32 + (gq << 3);
        bf16x8 af[4], bfr[4];
#pragma unroll
        for (int nt = 0; nt < 4; nt++) bfr[nt] = *(const bf16x8*)(pb + nt * 512);
#pragma unroll
        for (int mt = 0; mt < 4; mt++) af[mt] = *(const bf16x8*)(pa + mt * 512);
        __builtin_amdgcn_s_setprio(1);
#pragma unroll
        for (int mt = 0; mt < 4; mt++)
#pragma unroll
            for (int nt = 0; nt < 4; nt++)
                acc[mt][nt] = __builtin_amdgcn_mfma_f32_16x16x32_bf16(af[mt], bfr[nt], acc[mt][nt], 0, 0, 0);
        __builtin_amdgcn_s_setprio(0);
        buf++; if (buf == 3) buf = 0;
    }
#undef ST_A128
#undef ST_B128
#undef LDSP

#pragma unroll
    for (int mt = 0; mt < 4; mt++) {
#pragma unroll
        for (int nt = 0; nt < 4; nt++) {
            int col = n0 + (wn << 6) + (nt << 4) + lr;
            float sc = (col < split) ? scale : 1.0f;
            float bv = bias ? bias[col] : 0.0f;
#pragma unroll
            for (int r = 0; r < 4; r++) {
                int row = m0 + (wm << 6) + (mt << 4) + (lg << 2) + r;
                if (row < M) {
                    float v = acc[mt][nt][r] * sc + bv;
                    if (vT && col >= vstart) vT[(size_t)(col - vstart) * 64 + row] = f2bf(v);
                    else if (c_f32) ((float*)C)[(size_t)row * N + col] = v;
                    else ((unsigned short*)C)[(size_t)row * N + col] = f2bf(v);
                }
            }
        }
    }
}

__global__ __launch_bounds__(256) void gemm128p(const unsigned short* __restrict__ A,
                                                const unsigned short* __restrict__ Bt,
                                                void* __restrict__ C,
                                                const float* __restrict__ bias,
                                                unsigned short* __restrict__ vT,
                                                int M, int N, int K, float scale, int split,
                                                int c_f32, int vstart) {
    __shared__ unsigned short lds[3 * 2 * 4096];
    gemm128p_body(A, Bt, C, bias, vT, M, N, K, scale, split, c_f32, vstart,
                  threadIdx.x, blockIdx.x, gridDim.x, lds);
}

// ---------------- mega: [0,24) qlkv gemm | [24,1048) 256x256 BK=64 8-phase GEMM ----------------
// gemm256 part identical to r9 (verified): K-half row-major to kb, V-half transposed to vbT.
__global__ __launch_bounds__(512, 2) void mega(const unsigned short* __restrict__ latb,
                                               const unsigned short* __restrict__ wqkvt,
                                               unsigned short* __restrict__ qlkvb,
                                               unsigned short* __restrict__ lvT,
                                               const unsigned short* __restrict__ A,
                                               const unsigned short* __restrict__ Bt,
                                               unsigned short* __restrict__ kb,
                                               unsigned short* __restrict__ vbT,
                                               int M, int N, int K) {
    __shared__ unsigned short lds[2][32768];  // 128 KiB

    if (blockIdx.x < 24) {
        // qlkv: [q | lk | lv] = latb @ wqkvt^T; q scaled 0.125; lv (cols>=2048) -> lvT transposed.
        gemm128p_body(latb, wqkvt, qlkvb, nullptr, lvT, 64, 3072, 1024, 0.125f, 1024, 0, 2048,
                      threadIdx.x & 255, blockIdx.x, 24, &lds[0][0]);
        return;
    }

    int nkt = K >> 6;
    int ntx = N >> 8;
    int nwg = (M >> 8) * (N >> 8);
    int bid = blockIdx.x - 24, swz = bid;
    if ((nwg & 7) == 0) { int cpx = nwg >> 3; swz = (bid & 7) * cpx + (bid >> 3); }
    int m0 = (swz / ntx) << 8, n0 = (swz % ntx) << 8;
    int tid = threadIdx.x, lane = tid & 63, w = tid >> 6;
    int wm = w >> 2, wn = w & 3;
    int lr = lane & 15, lg = lane >> 4;

    int srow = lane >> 3;
    int sg = (lane & 7) ^ srow;
    const unsigned short* aS = A + (size_t)(m0 + (w << 3) + srow) * K + (sg << 3);
    const unsigned short* bS = Bt + (size_t)(n0 + (w << 3) + srow) * K + (sg << 3);
    size_t rs64 = (size_t)64 * K;

    int baseA = (wm << 13) + lr * 64;
    int baseB = 16384 + (wn << 12) + lr * 64;
    int kg0 = (((0 << 2) + lg) ^ (lr & 7)) << 3;
    int kg1 = (((1 << 2) + lg) ^ (lr & 7)) << 3;

    f32x4 acc[8][4] = {};

#define ST_A(bi, kt) do { \
        gload_lds16(aS + ((size_t)(kt) << 6),          &lds[bi][(w << 9)]); \
        gload_lds16(aS + rs64 + ((size_t)(kt) << 6),   &lds[bi][4096 + (w << 9)]); \
        gload_lds16(aS + 2*rs64 + ((size_t)(kt) << 6), &lds[bi][8192 + (w << 9)]); \
        gload_lds16(aS + 3*rs64 + ((size_t)(kt) << 6), &lds[bi][12288 + (w << 9)]); } while (0)
#define ST_B(bi, kt) do { \
        gload_lds16(bS + ((size_t)(kt) << 6),          &lds[bi][16384 + (w << 9)]); \
        gload_lds16(bS + rs64 + ((size_t)(kt) << 6),   &lds[bi][20480 + (w << 9)]); \
        gload_lds16(bS + 2*rs64 + ((size_t)(kt) << 6), &lds[bi][24576 + (w << 9)]); \
        gload_lds16(bS + 3*rs64 + ((size_t)(kt) << 6), &lds[bi][28672 + (w << 9)]); } while (0)

    ST_A(0, 0);
    ST_B(0, 0);

    for (int t = 0; t < nkt; ++t) {
        int cur = t & 1, nxt = cur ^ 1;
        int st = t + 1; if (st >= nkt) st = nkt - 1;
        const unsigned short* L = &lds[cur][0];
        bf16x8 af[4], bfr[4];

        // ---- P0: stage A(t+1); vmcnt(4) publishes tile t; reads ks0 m0-3 + B ks0 ----
        ST_A(nxt, st);
        __builtin_amdgcn_sched_barrier(0);
        asm volatile("s_waitcnt vmcnt(4)" ::: "memory");
        __builtin_amdgcn_sched_barrier(0);
        __builtin_amdgcn_s_barrier();
        __builtin_amdgcn_sched_barrier(0);
#pragma unroll
        for (int nt = 0; nt < 4; nt++) bfr[nt] = *(const bf16x8*)(L + baseB + nt * 1024 + kg0);
#pragma unroll
        for (int i = 0; i < 4; i++) af[i] = *(const bf16x8*)(L + baseA + i * 1024 + kg0);
        asm volatile("s_waitcnt lgkmcnt(0)" ::: "memory");
        __builtin_amdgcn_sched_barrier(0);
        __builtin_amdgcn_s_setprio(1);
#pragma unroll
        for (int i = 0; i < 4; i++)
#pragma unroll
            for (int nt = 0; nt < 4; nt++)
                acc[i][nt] = __builtin_amdgcn_mfma_f32_16x16x32_bf16(af[i], bfr[nt], acc[i][nt], 0, 0, 0);
        __builtin_amdgcn_s_setprio(0);

        // ---- P1: stage B(t+1); reads ks0 m4-7 ----
        ST_B(nxt, st);
#pragma unroll
        for (int i = 0; i < 4; i++) af[i] = *(const bf16x8*)(L + baseA + (i + 4) * 1024 + kg0);
        asm volatile("s_waitcnt lgkmcnt(0)" ::: "memory");
        __builtin_amdgcn_sched_barrier(0);
        __builtin_amdgcn_s_setprio(1);
#pragma unroll
        for (int i = 0; i < 4; i++)
#pragma unroll
            for (int nt = 0; nt < 4; nt++)
                acc[i + 4][nt] = __builtin_amdgcn_mfma_f32_16x16x32_bf16(af[i], bfr[nt], acc[i + 4][nt], 0, 0, 0);
        __builtin_amdgcn_s_setprio(0);

        // ---- P2: reads ks1 m0-3 + B ks1 ----
#pragma unroll
        for (int nt = 0; nt < 4; nt++) bfr[nt] = *(const bf16x8*)(L + baseB + nt * 1024 + kg1);
#pragma unroll
        for (int i = 0; i < 4; i++) af[i] = *(const bf16x8*)(L + baseA + i * 1024 + kg1);
        asm volatile("s_waitcnt lgkmcnt(0)" ::: "memory");
        __builtin_amdgcn_sched_barrier(0);
        __builtin_amdgcn_s_setprio(1);
#pragma unroll
        for (int i = 0; i < 4; i++)
#pragma unroll
            for (int nt = 0; nt < 4; nt++)
                acc[i][nt] = __builtin_amdgcn_mfma_f32_16x16x32_bf16(af[i], bfr[nt], acc[i][nt], 0, 0, 0);
        __builtin_amdgcn_s_setprio(0);

        // ---- P3: reads ks1 m4-7; closing barrier after lgkmcnt ----
#pragma unroll
        for (int i = 0; i < 4; i++) af[i] = *(const bf16x8*)(L + baseA + (i + 4) * 1024 + kg1);
        asm volatile("s_waitcnt lgkmcnt(0)" ::: "memory");
        __builtin_amdgcn_sched_barrier(0);
        __builtin_amdgcn_s_barrier();
        __builtin_amdgcn_sched_barrier(0);
        __builtin_amdgcn_s_setprio(1);
#pragma unroll
        for (int i = 0; i < 4; i++)
#pragma unroll
            for (int nt = 0; nt < 4; nt++)
                acc[i + 4][nt] = __builtin_amdgcn_mfma_f32_16x16x32_bf16(af[i], bfr[nt], acc[i + 4][nt], 0, 0, 0);
        __builtin_amdgcn_s_setprio(0);
    }
#undef ST_A
#undef ST_B

    if (n0 < 1024) {
#pragma unroll
        for (int mt = 0; mt < 8; mt++) {
#pragma unroll
            for (int nt = 0; nt < 4; nt++) {
                int col = n0 + (wn << 6) + (nt << 4) + lr;
                size_t rbase = (size_t)(m0 + (wm << 7) + (mt << 4) + (lg << 2));
#pragma unroll
                for (int r = 0; r < 4; r++)
                    kb[(rbase + r) * 1024 + col] = f2bf(acc[mt][nt][r]);
            }
        }
    } else {
#pragma unroll
        for (int mt = 0; mt < 8; mt++) {
#pragma unroll
            for (int nt = 0; nt < 4; nt++) {
                int dg = n0 - 1024 + (wn << 6) + (nt << 4) + lr;
                int rbase = m0 + (wm << 7) + (mt << 4) + (lg << 2);
                int bm = rbase >> 10, j = rbase & 1023;
                u16x4 o;
                o.x = f2bf(acc[mt][nt][0]); o.y = f2bf(acc[mt][nt][1]);
                o.z = f2bf(acc[mt][nt][2]); o.w = f2bf(acc[mt][nt][3]);
                *(u16x4*)(&vbT[((size_t)(bm << 10) + dg) * 1024 + j]) = o;
            }
        }
    }
}

// ---------------- fused flash attention over 1088 keys (unchanged from r9) ----------------
__global__ __launch_bounds__(256) void attn_kernel(const unsigned short* __restrict__ qg, int qstride,
                                                   const unsigned short* __restrict__ kb,
                                                   const unsigned short* __restrict__ vbT,
                                                   const unsigned short* __restrict__ lkg, int lstride,
                                                   const unsigned short* __restrict__ lvT,
                                                   unsigned short* __restrict__ og) {
    __shared__ unsigned short K_lds[64 * 72];
    __shared__ unsigned short V_lds[64 * 72];
    __shared__ unsigned short P_lds[4][16 * 72];
    int bm = blockIdx.x >> 4, h = blockIdx.x & 15;
    int tid = threadIdx.x, lane = tid & 63, w = tid >> 6;
    int lr = lane & 15, lg = lane >> 4;

    bf16x8 qf[2];
#pragma unroll
    for (int kk = 0; kk < 2; kk++)
        qf[kk] = *(const bf16x8*)(qg + (size_t)((w << 4) + lr) * qstride + (h << 6) + (kk << 5) + (lg << 3));

    f32x4 acc[4] = {};
    float m_run[4], l_run[4];
#pragma unroll
    for (int r = 0; r < 4; r++) { m_run[r] = -1e30f; l_run[r] = 0.0f; }

    int jrow = tid >> 2;
    int seg = (tid & 3) << 4;

    const unsigned short* k_s = kb + (size_t)((bm << 10) + jrow) * 1024 + (h << 6) + seg;
    const unsigned short* v_s = vbT + (size_t)((bm << 10) + (h << 6) + jrow) * 1024 + seg;
    u16x8 k0 = *(const u16x8*)(k_s);
    u16x8 k1 = *(const u16x8*)(k_s + 8);
    u16x8 v0 = *(const u16x8*)(v_s);
    u16x8 v1 = *(const u16x8*)(v_s + 8);

    for (int t = 0; t < 17; t++) {
        *(u16x8*)(&K_lds[jrow * 72 + seg]) = k0;
        *(u16x8*)(&K_lds[jrow * 72 + seg + 8]) = k1;
        *(u16x8*)(&V_lds[jrow * 72 + seg]) = v0;
        *(u16x8*)(&V_lds[jrow * 72 + seg + 8]) = v1;
        __syncthreads();

        u16x8 nk0 = k0, nk1 = k1, nv0 = v0, nv1 = v1;
        if (t < 16) {
            if (t < 15) {
                const unsigned short* ks = kb + (size_t)((bm << 10) + ((t + 1) << 6) + jrow) * 1024 + (h << 6) + seg;
                const unsigned short* vs = vbT + (size_t)((bm << 10) + (h << 6) + jrow) * 1024 + ((t + 1) << 6) + seg;
                nk0 = *(const u16x8*)(ks);
                nk1 = *(const u16x8*)(ks + 8);
                nv0 = *(const u16x8*)(vs);
                nv1 = *(const u16x8*)(vs + 8);
            } else {
                const unsigned short* ks = lkg + (size_t)jrow * lstride + (h << 6) + seg;
                const unsigned short* vs = lvT + (size_t)((h << 6) + jrow) * 64 + seg;
                nk0 = *(const u16x8*)(ks);
                nk1 = *(const u16x8*)(ks + 8);
                nv0 = *(const u16x8*)(vs);
                nv1 = *(const u16x8*)(vs + 8);
            }
        }

        f32x4 s[4] = {};
#pragma unroll
        for (int jt = 0; jt < 4; jt++) {
#pragma unroll
            for (int kk = 0; kk < 2; kk++) {
                bf16x8 kf = *(const bf16x8*)(&K_lds[(size_t)((jt << 4) + lr) * 72 + (kk << 5) + (lg << 3)]);
                s[jt] = __builtin_amdgcn_mfma_f32_16x16x32_bf16(qf[kk], kf, s[jt], 0, 0, 0);
            }
        }
#pragma unroll
        for (int r = 0; r < 4; r++) {
            float mx = fmaxf(fmaxf(s[0][r], s[1][r]), fmaxf(s[2][r], s[3][r]));
            mx = fmaxf(mx, __shfl_xor(mx, 1));
            mx = fmaxf(mx, __shfl_xor(mx, 2));
            mx = fmaxf(mx, __shfl_xor(mx, 4));
            mx = fmaxf(mx, __shfl_xor(mx, 8));
            float nm = fmaxf(m_run[r], mx);
            float fct = __expf(m_run[r] - nm);
            m_run[r] = nm;
            float p0 = __expf(s[0][r] - nm);
            float p1 = __expf(s[1][r] - nm);
            float p2 = __expf(s[2][r] - nm);
            float p3 = __expf(s[3][r] - nm);
            float sum = p0 + p1 + p2 + p3;
            sum += __shfl_xor(sum, 1);
            sum += __shfl_xor(sum, 2);
            sum += __shfl_xor(sum, 4);
            sum += __shfl_xor(sum, 8);
            l_run[r] = l_run[r] * fct + sum;
#pragma unroll
            for (int dt = 0; dt < 4; dt++) acc[dt][r] *= fct;
            int prow = ((lg << 2) + r) * 72;
            P_lds[w][prow + lr]      = f2bf(p0);
            P_lds[w][prow + 16 + lr] = f2bf(p1);
            P_lds[w][prow + 32 + lr] = f2bf(p2);
            P_lds[w][prow + 48 + lr] = f2bf(p3);
        }
#pragma unroll
        for (int jkk = 0; jkk < 2; jkk++) {
            bf16x8 pf = *(const bf16x8*)(&P_lds[w][(size_t)lr * 72 + (jkk << 5) + (lg << 3)]);
#pragma unroll
            for (int dt = 0; dt < 4; dt++) {
                bf16x8 vf = *(const bf16x8*)(&V_lds[(size_t)((dt << 4) + lr) * 72 + (jkk << 5) + (lg << 3)]);
                acc[dt] = __builtin_amdgcn_mfma_f32_16x16x32_bf16(pf, vf, acc[dt], 0, 0, 0);
            }
        }
        __syncthreads();
        k0 = nk0; k1 = nk1; v0 = nv0; v1 = nv1;
    }
#pragma unroll
    for (int dt = 0; dt < 4; dt++) {
#pragma unroll
        for (int r = 0; r < 4; r++) {
            int i = (w << 4) + (lg << 2) + r;
            float v = acc[dt][r] / l_run[r];
            og[(size_t)((bm << 6) + i) * 1024 + (h << 6) + (dt << 4) + lr] = f2bf(v);
        }
    }
}

extern "C" void kernel_launch(void* const* d_in, const int* in_sizes, int n_in,
                              void* d_out, int out_size, void* d_ws, size_t ws_size,
                              hipStream_t stream) {
    const float* x       = (const float*)d_in[0];
    const float* latents = (const float*)d_in[1];
    const float* Wq      = (const float*)d_in[2];
    const float* Wkv     = (const float*)d_in[3];
    const float* Wout    = (const float*)d_in[4];
    const float* bout    = (const float*)d_in[5];
    char* ws = (char*)d_ws;
    unsigned short* xb    = (unsigned short*)(ws);                 // 64 MiB  [32768][1024]
    unsigned short* kb    = (unsigned short*)(ws + 67108864);      // 64 MiB  [32768][1024]
    unsigned short* vbT   = (unsigned short*)(ws + 134217728);     // 64 MiB  [32][1024 dg][1024 j]
    unsigned short* wqkvt = (unsigned short*)(ws + 201326592);     // 6 MiB   [3072][1024]
    unsigned short* wkvt  = wqkvt + 1024 * 1024;                   //         rows 1024..3071
    unsigned short* woutt = (unsigned short*)(ws + 207618048);     // 2 MiB   [1024][1024]
    unsigned short* latb  = (unsigned short*)(ws + 209715200);     // 128 KiB [64][1024]
    unsigned short* qlkvb = (unsigned short*)(ws + 209846272);     // 384 KiB [64][3072] (q | lk | --)
    unsigned short* attnb = (unsigned short*)(ws + 210239488);     // 4 MiB   [2048][1024]
    unsigned short* lvT   = (unsigned short*)(ws + 214433792);     // 128 KiB [1024 d2][64 j]

    // 1) all input conversions/transposes in one launch
    prep<<<6208, 256, 0, stream>>>(x, latents, Wq, Wkv, Wout, xb, latb, wqkvt, wkvt, woutt);
    // 2) qlkv gemm (24 blocks) + dominant kv gemm (1024 blocks) in one launch
    mega<<<1048, 512, 0, stream>>>(latb, wqkvt, qlkvb, lvT, xb, wkvt, kb, vbT, 32768, 2048, 1024);
    // 3) fused attention
    attn_kernel<<<512, 256, 0, stream>>>(qlkvb, 3072, kb, vbT, qlkvb + 1024, 3072, lvT, attnb);
    // 4) out = attnout @ Wout + bout (fp32 out)
    gemm128p<<<128, 256, 0, stream>>>(attnb, woutt, (void*)d_out, bout, nullptr, 2048, 1024, 1024, 1.0f, 0, 1, 1 << 30);
}

// Round 11
// 240.394 us; speedup vs baseline: 1.1323x; 1.0061x over previous
//
#include <hip/hip_runtime.h>
#include <cstdint>

typedef __attribute__((ext_vector_type(8))) __bf16 bf16x8;
typedef __attribute__((ext_vector_type(4))) float f32x4;
typedef __attribute__((ext_vector_type(8))) unsigned short u16x8;
typedef __attribute__((ext_vector_type(4))) unsigned short u16x4;

__device__ __forceinline__ unsigned short f2bf(float f) {
    union { float f; unsigned u; } v; v.f = f;
    unsigned u = v.u;
    return (unsigned short)((u + 0x7FFFu + ((u >> 16) & 1u)) >> 16);
}

__device__ __forceinline__ void gload_lds16(const void* g, void* l) {
    auto gp = reinterpret_cast<__attribute__((address_space(1))) unsigned*>(
        reinterpret_cast<uintptr_t>(g));
    auto lp = reinterpret_cast<__attribute__((address_space(3))) unsigned*>(
        reinterpret_cast<uintptr_t>(l));
    __builtin_amdgcn_global_load_lds(gp, lp, 16, 0, 0);
}

// ---------------- fused prep: cvt x | cvt latents | W transposes (one launch) ----------------
__global__ __launch_bounds__(256) void prep(const float* __restrict__ x,
                                            const float* __restrict__ latents,
                                            const float* __restrict__ Wq,
                                            const float* __restrict__ Wkv,
                                            const float* __restrict__ Wout,
                                            unsigned short* __restrict__ xb,
                                            unsigned short* __restrict__ latb,
                                            unsigned short* __restrict__ wqkvt,
                                            unsigned short* __restrict__ wkvt,
                                            unsigned short* __restrict__ woutt) {
    int b = blockIdx.x, tid = threadIdx.x;
    if (b < 2048) {                       // cvt x: 33554432 elems = 8388608 float4
        int idx = b * 256 + tid, stride = 2048 * 256;
        for (int i = idx; i < 8388608; i += stride) {
            float4 v = ((const float4*)x)[i];
            u16x4 o;
            o.x = f2bf(v.x); o.y = f2bf(v.y); o.z = f2bf(v.z); o.w = f2bf(v.w);
            ((u16x4*)xb)[i] = o;
        }
        return;
    }
    b -= 2048;
    if (b < 64) {                         // cvt latents: 16384 float4
        int i = b * 256 + tid;
        float4 v = ((const float4*)latents)[i];
        u16x4 o;
        o.x = f2bf(v.x); o.y = f2bf(v.y); o.z = f2bf(v.z); o.w = f2bf(v.w);
        ((u16x4*)latb)[i] = o;
        return;
    }
    b -= 64;
    const float* in; unsigned short* out; int R, C, bx, by;
    if (b < 1024)      { in = Wq;   out = wqkvt; R = 1024; C = 1024; bx = b & 31; by = b >> 5; }
    else if (b < 3072) { int v = b - 1024; in = Wkv;  out = wkvt;  R = 1024; C = 2048; bx = v & 63; by = v >> 6; }
    else               { int v = b - 3072; in = Wout; out = woutt; R = 1024; C = 1024; bx = v & 31; by = v >> 5; }
    __shared__ float t[32][33];
    int c0 = bx * 32, r0 = by * 32;
    int tx = tid & 31, ty = tid >> 5;
    for (int i = ty; i < 32; i += 8)
        t[i][tx] = in[(size_t)(r0 + i) * C + c0 + tx];
    __syncthreads();
    for (int i = ty; i < 32; i += 8)
        out[(size_t)(c0 + i) * R + r0 + tx] = f2bf(t[tx][i]);
}

// ---------------- pipelined 128x128 bf16 GEMM body (triple-buffer, counted vmcnt) ----
// tid is a VIRTUAL 256-thread id (512-thread callers pass tid&255: waves 4-7 mirror 0-3 —
// duplicate DMA/stores of identical data to identical addresses, barrier-safe).
__device__ __forceinline__ void gemm128p_body(const unsigned short* __restrict__ A,
                                              const unsigned short* __restrict__ Bt,
                                              void* __restrict__ C,
                                              const float* __restrict__ bias,
                                              unsigned short* __restrict__ vT,
                                              int M, int N, int K, float scale, int split,
                                              int c_f32, int vstart,
                                              int tid, int bid, int nwg,
                                              unsigned short* ldsbuf) {
#define LDSP(bi, half) (ldsbuf + ((bi) * 2 + (half)) * 4096)
    int ntx = N >> 7;
    int swz = bid;
    if ((nwg & 7) == 0) { int cpx = nwg >> 3; swz = (bid & 7) * cpx + (bid >> 3); }
    int m0 = (swz / ntx) << 7, n0 = (swz % ntx) << 7;
    int lane = tid & 63, w = tid >> 6;
    int wm = w >> 1, wn = w & 1;
    int lr = lane & 15, lg = lane >> 4;
    int gq = lg ^ ((lr >> 1) & 3);
    int nkt = K >> 5;

    int arow = tid >> 2;
    int sgl = (tid & 3) ^ ((arow >> 1) & 3);
    int ra0 = m0 + arow;      if (ra0 > M - 1) ra0 = M - 1;
    int ra1 = m0 + 64 + arow; if (ra1 > M - 1) ra1 = M - 1;
    const unsigned short* a0 = A + (size_t)ra0 * K + (sgl << 3);
    const unsigned short* a1 = A + (size_t)ra1 * K + (sgl << 3);
    const unsigned short* b0 = Bt + (size_t)(n0 + arow) * K + (sgl << 3);
    const unsigned short* b1 = Bt + (size_t)(n0 + 64 + arow) * K + (sgl << 3);

    f32x4 acc[4][4] = {};

#define ST_A128(bi, kt) do { \
        gload_lds16(a0 + ((kt) << 5), LDSP(bi, 0) + (w << 9)); \
        gload_lds16(a1 + ((kt) << 5), LDSP(bi, 0) + 2048 + (w << 9)); } while (0)
#define ST_B128(bi, kt) do { \
        gload_lds16(b0 + ((kt) << 5), LDSP(bi, 1) + (w << 9)); \
        gload_lds16(b1 + ((kt) << 5), LDSP(bi, 1) + 2048 + (w << 9)); } while (0)

    ST_A128(0, 0); ST_B128(0, 0);
    ST_A128(1, 1); ST_B128(1, 1);

    int buf = 0;
    for (int t = 0; t < nkt; ++t) {
        asm volatile("s_waitcnt vmcnt(4) lgkmcnt(0)" ::: "memory");
        __builtin_amdgcn_sched_barrier(0);
        __builtin_amdgcn_s_barrier();
        __builtin_amdgcn_sched_barrier(0);
        int st = t + 2; if (st >= nkt) st = nkt - 1;
        int sbuf = buf + 2; if (sbuf >= 3) sbuf -= 3;
        ST_A128(sbuf, st);
        ST_B128(sbuf, st);
        const unsigned short* pa = LDSP(buf, 0) + ((wm << 6) + lr) * 32 + (gq << 3);
        const unsigned short* pb = LDSP(buf, 1) + ((wn << 6) + lr) * 32 + (gq << 3);
        bf16x8 af[4], bfr[4];
#pragma unroll
        for (int nt = 0; nt < 4; nt++) bfr[nt] = *(const bf16x8*)(pb + nt * 512);
#pragma unroll
        for (int mt = 0; mt < 4; mt++) af[mt] = *(const bf16x8*)(pa + mt * 512);
        __builtin_amdgcn_s_setprio(1);
#pragma unroll
        for (int mt = 0; mt < 4; mt++)
#pragma unroll
            for (int nt = 0; nt < 4; nt++)
                acc[mt][nt] = __builtin_amdgcn_mfma_f32_16x16x32_bf16(af[mt], bfr[nt], acc[mt][nt], 0, 0, 0);
        __builtin_amdgcn_s_setprio(0);
        buf++; if (buf == 3) buf = 0;
    }
#undef ST_A128
#undef ST_B128
#undef LDSP

#pragma unroll
    for (int mt = 0; mt < 4; mt++) {
#pragma unroll
        for (int nt = 0; nt < 4; nt++) {
            int col = n0 + (wn << 6) + (nt << 4) + lr;
            float sc = (col < split) ? scale : 1.0f;
            float bv = bias ? bias[col] : 0.0f;
#pragma unroll
            for (int r = 0; r < 4; r++) {
                int row = m0 + (wm << 6) + (mt << 4) + (lg << 2) + r;
                if (row < M) {
                    float v = acc[mt][nt][r] * sc + bv;
                    if (vT && col >= vstart) vT[(size_t)(col - vstart) * 64 + row] = f2bf(v);
                    else if (c_f32) ((float*)C)[(size_t)row * N + col] = v;
                    else ((unsigned short*)C)[(size_t)row * N + col] = f2bf(v);
                }
            }
        }
    }
}

__global__ __launch_bounds__(256) void gemm128p(const unsigned short* __restrict__ A,
                                                const unsigned short* __restrict__ Bt,
                                                void* __restrict__ C,
                                                const float* __restrict__ bias,
                                                unsigned short* __restrict__ vT,
                                                int M, int N, int K, float scale, int split,
                                                int c_f32, int vstart) {
    __shared__ unsigned short lds[3 * 2 * 4096];
    gemm128p_body(A, Bt, C, bias, vT, M, N, K, scale, split, c_f32, vstart,
                  threadIdx.x, blockIdx.x, gridDim.x, lds);
}

// ---------------- mega: [0,24) qlkv gemm | [24,1048) 256x256 BK=64 GEMM ----------------
// r10 structure with interior lgkmcnt(0) drains REMOVED (compiler-managed ds_read->MFMA
// waits per m97); the two race-guard seams kept: P0 vmcnt(4)+barrier (tile publish),
// P3 lgkmcnt(0)+barrier (read-completion publish before next iter's overwrite).
__global__ __launch_bounds__(512, 2) void mega(const unsigned short* __restrict__ latb,
                                               const unsigned short* __restrict__ wqkvt,
                                               unsigned short* __restrict__ qlkvb,
                                               unsigned short* __restrict__ lvT,
                                               const unsigned short* __restrict__ A,
                                               const unsigned short* __restrict__ Bt,
                                               unsigned short* __restrict__ kb,
                                               unsigned short* __restrict__ vbT,
                                               int M, int N, int K) {
    __shared__ unsigned short lds[2][32768];  // 128 KiB

    if (blockIdx.x < 24) {
        gemm128p_body(latb, wqkvt, qlkvb, nullptr, lvT, 64, 3072, 1024, 0.125f, 1024, 0, 2048,
                      threadIdx.x & 255, blockIdx.x, 24, &lds[0][0]);
        return;
    }

    int nkt = K >> 6;
    int ntx = N >> 8;
    int nwg = (M >> 8) * (N >> 8);
    int bid = blockIdx.x - 24, swz = bid;
    if ((nwg & 7) == 0) { int cpx = nwg >> 3; swz = (bid & 7) * cpx + (bid >> 3); }
    int m0 = (swz / ntx) << 8, n0 = (swz % ntx) << 8;
    int tid = threadIdx.x, lane = tid & 63, w = tid >> 6;
    int wm = w >> 2, wn = w & 3;
    int lr = lane & 15, lg = lane >> 4;

    int srow = lane >> 3;
    int sg = (lane & 7) ^ srow;
    const unsigned short* aS = A + (size_t)(m0 + (w << 3) + srow) * K + (sg << 3);
    const unsigned short* bS = Bt + (size_t)(n0 + (w << 3) + srow) * K + (sg << 3);
    size_t rs64 = (size_t)64 * K;

    int baseA = (wm << 13) + lr * 64;
    int baseB = 16384 + (wn << 12) + lr * 64;
    int kg0 = (((0 << 2) + lg) ^ (lr & 7)) << 3;
    int kg1 = (((1 << 2) + lg) ^ (lr & 7)) << 3;

    f32x4 acc[8][4] = {};

#define ST_A(bi, kt) do { \
        gload_lds16(aS + ((size_t)(kt) << 6),          &lds[bi][(w << 9)]); \
        gload_lds16(aS + rs64 + ((size_t)(kt) << 6),   &lds[bi][4096 + (w << 9)]); \
        gload_lds16(aS + 2*rs64 + ((size_t)(kt) << 6), &lds[bi][8192 + (w << 9)]); \
        gload_lds16(aS + 3*rs64 + ((size_t)(kt) << 6), &lds[bi][12288 + (w << 9)]); } while (0)
#define ST_B(bi, kt) do { \
        gload_lds16(bS + ((size_t)(kt) << 6),          &lds[bi][16384 + (w << 9)]); \
        gload_lds16(bS + rs64 + ((size_t)(kt) << 6),   &lds[bi][20480 + (w << 9)]); \
        gload_lds16(bS + 2*rs64 + ((size_t)(kt) << 6), &lds[bi][24576 + (w << 9)]); \
        gload_lds16(bS + 3*rs64 + ((size_t)(kt) << 6), &lds[bi][28672 + (w << 9)]); } while (0)

    ST_A(0, 0);
    ST_B(0, 0);

    for (int t = 0; t < nkt; ++t) {
        int cur = t & 1, nxt = cur ^ 1;
        int st = t + 1; if (st >= nkt) st = nkt - 1;
        const unsigned short* L = &lds[cur][0];
        bf16x8 af[4], bfr[4];

        // ---- P0: stage A(t+1); vmcnt(4) publishes tile t; reads + MFMA (compiler waits) ----
        ST_A(nxt, st);
        __builtin_amdgcn_sched_barrier(0);
        asm volatile("s_waitcnt vmcnt(4)" ::: "memory");
        __builtin_amdgcn_sched_barrier(0);
        __builtin_amdgcn_s_barrier();
        __builtin_amdgcn_sched_barrier(0);
#pragma unroll
        for (int nt = 0; nt < 4; nt++) bfr[nt] = *(const bf16x8*)(L + baseB + nt * 1024 + kg0);
#pragma unroll
        for (int i = 0; i < 4; i++) af[i] = *(const bf16x8*)(L + baseA + i * 1024 + kg0);
        __builtin_amdgcn_s_setprio(1);
#pragma unroll
        for (int i = 0; i < 4; i++)
#pragma unroll
            for (int nt = 0; nt < 4; nt++)
                acc[i][nt] = __builtin_amdgcn_mfma_f32_16x16x32_bf16(af[i], bfr[nt], acc[i][nt], 0, 0, 0);
        __builtin_amdgcn_s_setprio(0);

        // ---- P1: stage B(t+1); reads ks0 m4-7; MFMA ----
        ST_B(nxt, st);
#pragma unroll
        for (int i = 0; i < 4; i++) af[i] = *(const bf16x8*)(L + baseA + (i + 4) * 1024 + kg0);
        __builtin_amdgcn_s_setprio(1);
#pragma unroll
        for (int i = 0; i < 4; i++)
#pragma unroll
            for (int nt = 0; nt < 4; nt++)
                acc[i + 4][nt] = __builtin_amdgcn_mfma_f32_16x16x32_bf16(af[i], bfr[nt], acc[i + 4][nt], 0, 0, 0);
        __builtin_amdgcn_s_setprio(0);

        // ---- P2: reads ks1 m0-3 + B ks1; MFMA ----
#pragma unroll
        for (int nt = 0; nt < 4; nt++) bfr[nt] = *(const bf16x8*)(L + baseB + nt * 1024 + kg1);
#pragma unroll
        for (int i = 0; i < 4; i++) af[i] = *(const bf16x8*)(L + baseA + i * 1024 + kg1);
        __builtin_amdgcn_s_setprio(1);
#pragma unroll
        for (int i = 0; i < 4; i++)
#pragma unroll
            for (int nt = 0; nt < 4; nt++)
                acc[i][nt] = __builtin_amdgcn_mfma_f32_16x16x32_bf16(af[i], bfr[nt], acc[i][nt], 0, 0, 0);
        __builtin_amdgcn_s_setprio(0);

        // ---- P3: reads ks1 m4-7; lgkmcnt(0)+barrier = read-completion seam; MFMA ----
#pragma unroll
        for (int i = 0; i < 4; i++) af[i] = *(const bf16x8*)(L + baseA + (i + 4) * 1024 + kg1);
        asm volatile("s_waitcnt lgkmcnt(0)" ::: "memory");
        __builtin_amdgcn_sched_barrier(0);
        __builtin_amdgcn_s_barrier();
        __builtin_amdgcn_sched_barrier(0);
        __builtin_amdgcn_s_setprio(1);
#pragma unroll
        for (int i = 0; i < 4; i++)
#pragma unroll
            for (int nt = 0; nt < 4; nt++)
                acc[i + 4][nt] = __builtin_amdgcn_mfma_f32_16x16x32_bf16(af[i], bfr[nt], acc[i + 4][nt], 0, 0, 0);
        __builtin_amdgcn_s_setprio(0);
    }
#undef ST_A
#undef ST_B

    if (n0 < 1024) {
#pragma unroll
        for (int mt = 0; mt < 8; mt++) {
#pragma unroll
            for (int nt = 0; nt < 4; nt++) {
                int col = n0 + (wn << 6) + (nt << 4) + lr;
                size_t rbase = (size_t)(m0 + (wm << 7) + (mt << 4) + (lg << 2));
#pragma unroll
                for (int r = 0; r < 4; r++)
                    kb[(rbase + r) * 1024 + col] = f2bf(acc[mt][nt][r]);
            }
        }
    } else {
#pragma unroll
        for (int mt = 0; mt < 8; mt++) {
#pragma unroll
            for (int nt = 0; nt < 4; nt++) {
                int dg = n0 - 1024 + (wn << 6) + (nt << 4) + lr;
                int rbase = m0 + (wm << 7) + (mt << 4) + (lg << 2);
                int bm = rbase >> 10, j = rbase & 1023;
                u16x4 o;
                o.x = f2bf(acc[mt][nt][0]); o.y = f2bf(acc[mt][nt][1]);
                o.z = f2bf(acc[mt][nt][2]); o.w = f2bf(acc[mt][nt][3]);
                *(u16x4*)(&vbT[((size_t)(bm << 10) + dg) * 1024 + j]) = o;
            }
        }
    }
}

// ---------------- fused flash attention over 1088 keys (unchanged) ----------------
__global__ __launch_bounds__(256) void attn_kernel(const unsigned short* __restrict__ qg, int qstride,
                                                   const unsigned short* __restrict__ kb,
                                                   const unsigned short* __restrict__ vbT,
                                                   const unsigned short* __restrict__ lkg, int lstride,
                                                   const unsigned short* __restrict__ lvT,
                                                   unsigned short* __restrict__ og) {
    __shared__ unsigned short K_lds[64 * 72];
    __shared__ unsigned short V_lds[64 * 72];
    __shared__ unsigned short P_lds[4][16 * 72];
    int bm = blockIdx.x >> 4, h = blockIdx.x & 15;
    int tid = threadIdx.x, lane = tid & 63, w = tid >> 6;
    int lr = lane & 15, lg = lane >> 4;

    bf16x8 qf[2];
#pragma unroll
    for (int kk = 0; kk < 2; kk++)
        qf[kk] = *(const bf16x8*)(qg + (size_t)((w << 4) + lr) * qstride + (h << 6) + (kk << 5) + (lg << 3));

    f32x4 acc[4] = {};
    float m_run[4], l_run[4];
#pragma unroll
    for (int r = 0; r < 4; r++) { m_run[r] = -1e30f; l_run[r] = 0.0f; }

    int jrow = tid >> 2;
    int seg = (tid & 3) << 4;

    const unsigned short* k_s = kb + (size_t)((bm << 10) + jrow) * 1024 + (h << 6) + seg;
    const unsigned short* v_s = vbT + (size_t)((bm << 10) + (h << 6) + jrow) * 1024 + seg;
    u16x8 k0 = *(const u16x8*)(k_s);
    u16x8 k1 = *(const u16x8*)(k_s + 8);
    u16x8 v0 = *(const u16x8*)(v_s);
    u16x8 v1 = *(const u16x8*)(v_s + 8);

    for (int t = 0; t < 17; t++) {
        *(u16x8*)(&K_lds[jrow * 72 + seg]) = k0;
        *(u16x8*)(&K_lds[jrow * 72 + seg + 8]) = k1;
        *(u16x8*)(&V_lds[jrow * 72 + seg]) = v0;
        *(u16x8*)(&V_lds[jrow * 72 + seg + 8]) = v1;
        __syncthreads();

        u16x8 nk0 = k0, nk1 = k1, nv0 = v0, nv1 = v1;
        if (t < 16) {
            if (t < 15) {
                const unsigned short* ks = kb + (size_t)((bm << 10) + ((t + 1) << 6) + jrow) * 1024 + (h << 6) + seg;
                const unsigned short* vs = vbT + (size_t)((bm << 10) + (h << 6) + jrow) * 1024 + ((t + 1) << 6) + seg;
                nk0 = *(const u16x8*)(ks);
                nk1 = *(const u16x8*)(ks + 8);
                nv0 = *(const u16x8*)(vs);
                nv1 = *(const u16x8*)(vs + 8);
            } else {
                const unsigned short* ks = lkg + (size_t)jrow * lstride + (h << 6) + seg;
                const unsigned short* vs = lvT + (size_t)((h << 6) + jrow) * 64 + seg;
                nk0 = *(const u16x8*)(ks);
                nk1 = *(const u16x8*)(ks + 8);
                nv0 = *(const u16x8*)(vs);
                nv1 = *(const u16x8*)(vs + 8);
            }
        }

        f32x4 s[4] = {};
#pragma unroll
        for (int jt = 0; jt < 4; jt++) {
#pragma unroll
            for (int kk = 0; kk < 2; kk++) {
                bf16x8 kf = *(const bf16x8*)(&K_lds[(size_t)((jt << 4) + lr) * 72 + (kk << 5) + (lg << 3)]);
                s[jt] = __builtin_amdgcn_mfma_f32_16x16x32_bf16(qf[kk], kf, s[jt], 0, 0, 0);
            }
        }
#pragma unroll
        for (int r = 0; r < 4; r++) {
            float mx = fmaxf(fmaxf(s[0][r], s[1][r]), fmaxf(s[2][r], s[3][r]));
            mx = fmaxf(mx, __shfl_xor(mx, 1));
            mx = fmaxf(mx, __shfl_xor(mx, 2));
            mx = fmaxf(mx, __shfl_xor(mx, 4));
            mx = fmaxf(mx, __shfl_xor(mx, 8));
            float nm = fmaxf(m_run[r], mx);
            float fct = __expf(m_run[r] - nm);
            m_run[r] = nm;
            float p0 = __expf(s[0][r] - nm);
            float p1 = __expf(s[1][r] - nm);
            float p2 = __expf(s[2][r] - nm);
            float p3 = __expf(s[3][r] - nm);
            float sum = p0 + p1 + p2 + p3;
            sum += __shfl_xor(sum, 1);
            sum += __shfl_xor(sum, 2);
            sum += __shfl_xor(sum, 4);
            sum += __shfl_xor(sum, 8);
            l_run[r] = l_run[r] * fct + sum;
#pragma unroll
            for (int dt = 0; dt < 4; dt++) acc[dt][r] *= fct;
            int prow = ((lg << 2) + r) * 72;
            P_lds[w][prow + lr]      = f2bf(p0);
            P_lds[w][prow + 16 + lr] = f2bf(p1);
            P_lds[w][prow + 32 + lr] = f2bf(p2);
            P_lds[w][prow + 48 + lr] = f2bf(p3);
        }
#pragma unroll
        for (int jkk = 0; jkk < 2; jkk++) {
            bf16x8 pf = *(const bf16x8*)(&P_lds[w][(size_t)lr * 72 + (jkk << 5) + (lg << 3)]);
#pragma unroll
            for (int dt = 0; dt < 4; dt++) {
                bf16x8 vf = *(const bf16x8*)(&V_lds[(size_t)((dt << 4) + lr) * 72 + (jkk << 5) + (lg << 3)]);
                acc[dt] = __builtin_amdgcn_mfma_f32_16x16x32_bf16(pf, vf, acc[dt], 0, 0, 0);
            }
        }
        __syncthreads();
        k0 = nk0; k1 = nk1; v0 = nv0; v1 = nv1;
    }
#pragma unroll
    for (int dt = 0; dt < 4; dt++) {
#pragma unroll
        for (int r = 0; r < 4; r++) {
            int i = (w << 4) + (lg << 2) + r;
            float v = acc[dt][r] / l_run[r];
            og[(size_t)((bm << 6) + i) * 1024 + (h << 6) + (dt << 4) + lr] = f2bf(v);
        }
    }
}

extern "C" void kernel_launch(void* const* d_in, const int* in_sizes, int n_in,
                              void* d_out, int out_size, void* d_ws, size_t ws_size,
                              hipStream_t stream) {
    const float* x       = (const float*)d_in[0];
    const float* latents = (const float*)d_in[1];
    const float* Wq      = (const float*)d_in[2];
    const float* Wkv     = (const float*)d_in[3];
    const float* Wout    = (const float*)d_in[4];
    const float* bout    = (const float*)d_in[5];
    char* ws = (char*)d_ws;
    unsigned short* xb    = (unsigned short*)(ws);                 // 64 MiB  [32768][1024]
    unsigned short* kb    = (unsigned short*)(ws + 67108864);      // 64 MiB  [32768][1024]
    unsigned short* vbT   = (unsigned short*)(ws + 134217728);     // 64 MiB  [32][1024 dg][1024 j]
    unsigned short* wqkvt = (unsigned short*)(ws + 201326592);     // 6 MiB   [3072][1024]
    unsigned short* wkvt  = wqkvt + 1024 * 1024;                   //         rows 1024..3071
    unsigned short* woutt = (unsigned short*)(ws + 207618048);     // 2 MiB   [1024][1024]
    unsigned short* latb  = (unsigned short*)(ws + 209715200);     // 128 KiB [64][1024]
    unsigned short* qlkvb = (unsigned short*)(ws + 209846272);     // 384 KiB [64][3072] (q | lk | --)
    unsigned short* attnb = (unsigned short*)(ws + 210239488);     // 4 MiB   [2048][1024]
    unsigned short* lvT   = (unsigned short*)(ws + 214433792);     // 128 KiB [1024 d2][64 j]

    // 1) all input conversions/transposes in one launch
    prep<<<6208, 256, 0, stream>>>(x, latents, Wq, Wkv, Wout, xb, latb, wqkvt, wkvt, woutt);
    // 2) qlkv gemm (24 blocks) + dominant kv gemm (1024 blocks) in one launch
    mega<<<1048, 512, 0, stream>>>(latb, wqkvt, qlkvb, lvT, xb, wkvt, kb, vbT, 32768, 2048, 1024);
    // 3) fused attention
    attn_kernel<<<512, 256, 0, stream>>>(qlkvb, 3072, kb, vbT, qlkvb + 1024, 3072, lvT, attnb);
    // 4) out = attnout @ Wout + bout (fp32 out)
    gemm128p<<<128, 256, 0, stream>>>(attnb, woutt, (void*)d_out, bout, nullptr, 2048, 1024, 1024, 1.0f, 0, 1, 1 << 30);
}